// Round 13
// baseline (317.609 us; speedup 1.0000x reference)
//
#include <hip/hip_runtime.h>
#include <hip/hip_fp16.h>

#define NN 100000
#define NE 3200000
#define FIN 512
#define HIDN 64
#define NC 16
#define LEAKY 0.2f
#define LG 0.2f

// MFMA MLP params
#define GM 128        // rows per block (4 waves x 32 rows)
#define HLD2 72       // H row stride in LDS (bf16 shorts, 144B = 16B-aligned)
#define MLP_BLKS 782  // ceil(100000/128)

// bucket sort params
#define BSH 9                 // 512 nodes per bucket
#define NBUCK 196             // ceil(100000/512)
#define TILE_A 2048
#define BHIST_BLKS 1024

typedef float4 f4;
typedef short bf16x8 __attribute__((ext_vector_type(8)));
typedef float f32x4 __attribute__((ext_vector_type(4)));
typedef unsigned short ushort_t;

__device__ __forceinline__ bf16x8 cvt8(const f4 a, const f4 b) {
  union { unsigned u[4]; bf16x8 v; } o;
  asm("v_cvt_pk_bf16_f32 %0, %1, %2" : "=v"(o.u[0]) : "v"(a.x), "v"(a.y));
  asm("v_cvt_pk_bf16_f32 %0, %1, %2" : "=v"(o.u[1]) : "v"(a.z), "v"(a.w));
  asm("v_cvt_pk_bf16_f32 %0, %1, %2" : "=v"(o.u[2]) : "v"(b.x), "v"(b.y));
  asm("v_cvt_pk_bf16_f32 %0, %1, %2" : "=v"(o.u[3]) : "v"(b.z), "v"(b.w));
  return o.v;
}

__device__ __forceinline__ float bf16f(ushort_t s) {
  return __uint_as_float(((unsigned)s) << 16);
}
__device__ __forceinline__ ushort_t f2bf(float f) {
  const unsigned u = __float_as_uint(f);
  return (ushort_t)((u + 0x7fffu + ((u >> 16) & 1u)) >> 16);   // RNE
}
// non-temporal 8B load of an (int,int) pair
__device__ __forceinline__ int2 ldnt(const int2* p) {
  const int* q = (const int*)p;
  int2 r;
  r.x = __builtin_nontemporal_load(q);
  r.y = __builtin_nontemporal_load(q + 1);
  return r;
}

// ---------------- prep: W0 -> W0^T bf16; zeroes bcnt + done ----------------
__global__ __launch_bounds__(256) void k_w0t(const float* __restrict__ W0,
                                             short* __restrict__ W0T,
                                             int* __restrict__ bcnt,
                                             int* __restrict__ done) {
  const int i = blockIdx.x*256 + threadIdx.x;   // i = c*512 + k
  if (blockIdx.x == 0) bcnt[threadIdx.x] = 0;   // k_bhist runs after us in-stream
  if (i == 0) *done = 0;
  if (i >= HIDN*FIN) return;
  const int c = i >> 9, k = i & 511;
  W0T[i] = (short)f2bf(W0[(size_t)k*HIDN + c]);
}

// ---------------- MLP: Z = relu(X@W0)@W1 ; R11 version (64KB Wb, 2 blocks/CU) ----------------
__global__ __launch_bounds__(256, 2) void k_mlp3(
    const float* __restrict__ X, const short* __restrict__ W0T,
    const float* __restrict__ W1, const float* __restrict__ a1v,
    const float* __restrict__ a2v, float* __restrict__ Z,
    ushort_t* __restrict__ Zb, float* __restrict__ f1o, float* __restrict__ f2o)
{
  __shared__ __align__(16) char smem[HIDN*FIN*2];       // 64 KB total
  short* Wb = (short*)smem;                             // XOR-swizzled bf16 W^T (k-loop)
  short (*HsB)[HLD2] = (short(*)[HLD2])smem;            // aliased after k-loop
  float* W1s = (float*)(smem + GM*HLD2*2);              // 4 KB, after HsB region
  const int t = threadIdx.x;
  const int wid = t >> 6, lane = t & 63;
  const int r = lane & 15, g = lane >> 4;
  const int rowbase = blockIdx.x*GM + wid*32;
  int row0 = rowbase + r;       if (row0 >= NN) row0 = NN-1;
  int row1 = rowbase + 16 + r;  if (row1 >= NN) row1 = NN-1;
  const float* pa0 = X + (size_t)row0*FIN + g*8;
  const float* pa1 = X + (size_t)row1*FIN + g*8;

  f4 xs[4][2][2];
  #pragma unroll
  for (int d=0; d<4; ++d) {
    xs[d][0][0] = *(const f4*)(pa0 + d*32);  xs[d][0][1] = *(const f4*)(pa0 + d*32 + 4);
    xs[d][1][0] = *(const f4*)(pa1 + d*32);  xs[d][1][1] = *(const f4*)(pa1 + d*32 + 4);
  }

  #pragma unroll
  for (int i2 = 0; i2 < 16; ++i2) {
    const int i = t + i2*256;
    const int row = i >> 6;
    const int cb = (i & 63) << 4;
    const bf16x8 v = *(const bf16x8*)(W0T + (size_t)row*FIN + (i & 63)*8);
    *(bf16x8*)((char*)Wb + row*1024 + (cb ^ ((row & 7) << 4))) = v;
  }
  __syncthreads();

  f32x4 acc[2][4];
  #pragma unroll
  for (int m=0;m<2;++m)
    #pragma unroll
    for (int n=0;n<4;++n) acc[m][n] = (f32x4){0.f,0.f,0.f,0.f};

  #pragma unroll
  for (int ks=0; ks<16; ++ks) {
    const int st = ks & 3;
    bf16x8 bh[4];
    #pragma unroll
    for (int n=0;n<4;++n) {
      const int wrow = n*16 + r;
      const int boff = wrow*1024 + ((ks*64 + g*16) ^ ((wrow & 7) << 4));
      bh[n] = *(const bf16x8*)((const char*)Wb + boff);
    }
    const bf16x8 xb0 = cvt8(xs[st][0][0], xs[st][0][1]);
    const bf16x8 xb1 = cvt8(xs[st][1][0], xs[st][1][1]);
    if (ks + 4 < 16) {
      const int ko = (ks+4)*32;
      xs[st][0][0] = *(const f4*)(pa0 + ko);  xs[st][0][1] = *(const f4*)(pa0 + ko + 4);
      xs[st][1][0] = *(const f4*)(pa1 + ko);  xs[st][1][1] = *(const f4*)(pa1 + ko + 4);
    }
    #pragma unroll
    for (int n=0;n<4;++n) {
      acc[0][n] = __builtin_amdgcn_mfma_f32_16x16x32_bf16(xb0, bh[n], acc[0][n], 0,0,0);
      acc[1][n] = __builtin_amdgcn_mfma_f32_16x16x32_bf16(xb1, bh[n], acc[1][n], 0,0,0);
    }
  }
  __syncthreads();   // all waves done reading Wb before overwrite with H

  #pragma unroll
  for (int m=0;m<2;++m) {
    const int hr = wid*32 + m*16 + g*4;
    #pragma unroll
    for (int n=0;n<4;++n)
      #pragma unroll
      for (int q=0;q<4;++q)
        HsB[hr+q][n*16+r] = (short)f2bf(fmaxf(acc[m][n][q], 0.f));
  }
  *(f4*)(W1s + t*4) = *(const f4*)(W1 + t*4);
  __syncthreads();

  // layer 2: 2 threads per node; thread handles 8 channels
  {
    const int en = t >> 1, half = t & 1;
    const int node = blockIdx.x*GM + en;
    if (node < NN) {
      float z[8];
      #pragma unroll
      for (int j=0;j<8;++j) z[j]=0.f;
      const bf16x8* hp = (const bf16x8*)(&HsB[en][0]);
      #pragma unroll
      for (int h8=0; h8<8; ++h8) {
        const bf16x8 hv8 = hp[h8];
        #pragma unroll
        for (int j=0;j<8;++j) {
          const float hv = bf16f((ushort_t)hv8[j]);
          const int h = h8*8 + j;
          const f4 wa = *(const f4*)(W1s + h*NC + half*8);
          const f4 wb = *(const f4*)(W1s + h*NC + half*8 + 4);
          z[0]+=hv*wa.x; z[1]+=hv*wa.y; z[2]+=hv*wa.z; z[3]+=hv*wa.w;
          z[4]+=hv*wb.x; z[5]+=hv*wb.y; z[6]+=hv*wb.z; z[7]+=hv*wb.w;
        }
      }
      f4* zp = (f4*)(Z + (size_t)node*NC + half*8);
      zp[0] = make_float4(z[0],z[1],z[2],z[3]);
      zp[1] = make_float4(z[4],z[5],z[6],z[7]);
      bf16x8 zb;
      #pragma unroll
      for (int j=0;j<8;++j) zb[j] = (short)f2bf(z[j]);
      *(bf16x8*)(Zb + (size_t)node*NC + half*8) = zb;
      float s1=0.f, s2=0.f;
      #pragma unroll
      for (int j=0;j<8;++j) { s1 += z[j]*a1v[half*8+j]; s2 += z[j]*a2v[half*8+j]; }
      s1 += __shfl_xor(s1, 1);
      s2 += __shfl_xor(s2, 1);
      if (half == 0) { f1o[node] = s1; f2o[node] = s2; }
    }
  }
}

// ---------------- CSR build: bucket histogram + fused scan (last block) ----------------
__global__ __launch_bounds__(256) void k_bhist(const int* __restrict__ src,
    int* __restrict__ bcnt, int* __restrict__ bbase, int* __restrict__ gcur,
    int* __restrict__ done) {
  __shared__ int c[256];
  __shared__ int isLast;
  const int t = threadIdx.x;
  c[t] = 0;
  __syncthreads();
  int i = blockIdx.x*256 + t;
  const int stride = gridDim.x*256;
  for (; i < NE; i += stride) atomicAdd(&c[src[i] >> BSH], 1);
  __syncthreads();
  if (t < NBUCK && c[t]) atomicAdd(&bcnt[t], c[t]);
  __threadfence();
  if (t == 0) isLast = (atomicAdd(done, 1) == (int)gridDim.x - 1);
  __syncthreads();
  if (!isLast) return;
  // last block: scan the 196 bucket counts (device-scope reads via atomic path)
  const int v = (t < NBUCK) ? atomicAdd(&bcnt[t], 0) : 0;
  c[t] = v;
  __syncthreads();
  for (int off=1; off<256; off<<=1) {
    const int x = (t>=off) ? c[t-off] : 0;
    __syncthreads();
    c[t] += x;
    __syncthreads();
  }
  if (t < NBUCK) { bbase[t] = c[t]-v; gcur[t] = c[t]-v; }
}

// ---------------- CSR build phase A: LDS multi-split into 196 buckets ----------------
__global__ __launch_bounds__(256) void k_binA(const int* __restrict__ src,
    const int* __restrict__ dst, const float* __restrict__ gcn,
    int* __restrict__ gcur, int2* __restrict__ tmp)
{
  __shared__ int cnt[256];
  __shared__ int scn[256];
  __shared__ int cur[256];
  __shared__ int gbase[256];
  __shared__ int2 stage[TILE_A];
  __shared__ unsigned char sb[TILE_A];
  const int t = threadIdx.x;
  const int e0 = blockIdx.x*TILE_A;
  const int ecount = min(TILE_A, NE - e0);
  cnt[t] = 0;
  __syncthreads();
  int w0v[8], w1v[8], bv[8];
  #pragma unroll
  for (int it=0; it<8; ++it) {
    const int i = e0 + it*256 + t;
    bv[it] = -1;
    if (i < NE) {
      const int s_ = src[i];
      const int b = s_ >> BSH;
      bv[it] = b;
      w0v[it] = dst[i] | ((s_ & ((1<<BSH)-1)) << 17);
      w1v[it] = __float_as_int(gcn[i]);
      atomicAdd(&cnt[b], 1);
    }
  }
  __syncthreads();
  scn[t] = cnt[t];
  __syncthreads();
  for (int off=1; off<256; off<<=1) {
    const int x = (t>=off) ? scn[t-off] : 0;
    __syncthreads();
    scn[t] += x;
    __syncthreads();
  }
  cur[t] = scn[t] - cnt[t];
  if (cnt[t] > 0) gbase[t] = atomicAdd(&gcur[t], cnt[t]);
  __syncthreads();
  #pragma unroll
  for (int it=0; it<8; ++it) {
    if (bv[it] >= 0) {
      const int pos = atomicAdd(&cur[bv[it]], 1);
      stage[pos] = make_int2(w0v[it], w1v[it]);
      sb[pos] = (unsigned char)bv[it];
    }
  }
  __syncthreads();
  #pragma unroll
  for (int it=0; it<8; ++it) {
    const int slot = it*256 + t;
    if (slot < ecount) {
      const int b = sb[slot];
      const int gd = gbase[b] + slot - (scn[b] - cnt[b]);
      tmp[gd] = stage[slot];
    }
  }
}

// ---------------- CSR build phase B: per-bucket fine sort, 1024 threads ----------------
__global__ __launch_bounds__(1024) void k_binB(const int* __restrict__ bbase,
    const int* __restrict__ bcnt, const int2* __restrict__ tmp,
    int* __restrict__ rowptr, int2* __restrict__ cvp)
{
  __shared__ int cnt[512];
  __shared__ int scn[512];
  __shared__ int cur[512];
  const int t = threadIdx.x;
  const int b = blockIdx.x;
  const int node0 = b << BSH;
  const int base = bbase[b];
  const int n = bcnt[b];
  if (t < 512) cnt[t] = 0;
  __syncthreads();
  for (int i = t; i < n; i += 1024)
    atomicAdd(&cnt[tmp[base+i].x >> 17], 1);
  __syncthreads();
  if (t < 512) scn[t] = cnt[t];
  __syncthreads();
  for (int off=1; off<512; off<<=1) {
    const int x = (t>=off && t<512) ? scn[t-off] : 0;
    __syncthreads();
    if (t < 512) scn[t] += x;
    __syncthreads();
  }
  if (t < 512) {
    const int excl = scn[t] - cnt[t];
    cur[t] = excl;
    if (node0 + t < NN) rowptr[node0 + t] = base + excl;
  }
  if (b == 0 && t == 0) rowptr[NN] = NE;
  __syncthreads();
  for (int i = t; i < n; i += 1024) {
    const int2 e = tmp[base+i];
    const int ls = e.x >> 17;
    const int p = base + atomicAdd(&cur[ls], 1);
    cvp[p] = make_int2(e.x & 0x1FFFF, e.y);
  }
}

// ---------------- hop 1: bf16 L2 gathers, batched-issue PV pipeline ----------------
__global__ __launch_bounds__(256) void k_hop(const int* __restrict__ rowptr,
    const int2* __restrict__ cvp,
    const ushort_t* __restrict__ Zb, const float* __restrict__ f1in,
    const float* __restrict__ f2in, ushort_t* __restrict__ Zoutb,
    float* __restrict__ f1out, float* __restrict__ f2out,
    const float* __restrict__ a1v, const float* __restrict__ a2v)
{
  __shared__ __align__(16) int2 rowbuf[8][64];
  const int t = threadIdx.x;
  const int lane = t & 31;
  const int hw = t >> 5;
  const int row = blockIdx.x*8 + hw;
  if (row >= NN) return;
  const int start = rowptr[row], end = rowptr[row+1];
  const int deg = end - start;
  const int c = lane & 15, g = (lane >> 4) & 1;

  if (deg == 0) {
    if (g == 0) {
      Zoutb[(size_t)row*NC + c] = 0;
      if (c == 0) { f1out[row] = 0.f; f2out[row] = 0.f; }
    }
    return;
  }
  const float f1r = f1in[row];

  if (deg <= 64) {
    int cc0 = 0, cc1 = 0; float vv0 = 0.f, vv1 = 0.f;
    float e0 = -1e30f, e1 = -1e30f;
    if (lane < deg) {
      const int2 p = ldnt(&cvp[start + lane]);
      cc0 = p.x; vv0 = __int_as_float(p.y);
      const float x = f1r + f2in[cc0];
      e0 = (x > 0.f) ? x : LEAKY*x;
    }
    if (32 + lane < deg) {
      const int2 p = ldnt(&cvp[start + 32 + lane]);
      cc1 = p.x; vv1 = __int_as_float(p.y);
      const float x = f1r + f2in[cc1];
      e1 = (x > 0.f) ? x : LEAKY*x;
    }
    float m = fmaxf(e0, e1);
    #pragma unroll
    for (int msk=1; msk<32; msk<<=1) m = fmaxf(m, __shfl_xor(m, msk));
    const float ex0 = (lane < deg) ? __expf(e0 - m) : 0.f;
    const float ex1 = (32 + lane < deg) ? __expf(e1 - m) : 0.f;
    float s = ex0 + ex1;
    #pragma unroll
    for (int msk=1; msk<32; msk<<=1) s += __shfl_xor(s, msk);
    const float lgs = LG / s;
    const int npass = (deg + 3) >> 2;
    if (lane < deg)
      rowbuf[hw][lane] = make_int2(cc0, __float_as_int((1.f-LG)*vv0 + ex0*lgs));
    if (32 + lane < deg)
      rowbuf[hw][32 + lane] = make_int2(cc1, __float_as_int((1.f-LG)*vv1 + ex1*lgs));
    for (int z = deg + lane; z < 4*npass; z += 32) rowbuf[hw][z] = make_int2(0, 0);
    asm volatile("s_waitcnt lgkmcnt(0)" ::: "memory");
    float accv = 0.f;
    for (int p0 = 0; p0 < npass; p0 += 8) {
      int4 pr[8]; ushort_t u0[8], u1[8];
      #pragma unroll
      for (int j=0;j<8;++j) {
        if (p0 + j < npass)
          pr[j] = *(const int4*)(&rowbuf[hw][(p0+j)*4 + g*2]);
        else
          pr[j] = make_int4(0, 0, 0, 0);
      }
      #pragma unroll
      for (int j=0;j<8;++j) {
        u0[j] = Zb[(size_t)pr[j].x*NC + c];
        u1[j] = Zb[(size_t)pr[j].z*NC + c];
      }
      #pragma unroll
      for (int j=0;j<8;++j) {
        accv += __int_as_float(pr[j].y) * bf16f(u0[j]);
        accv += __int_as_float(pr[j].w) * bf16f(u1[j]);
      }
    }
    accv += __shfl_xor(accv, 16);
    if (g == 0) {
      Zoutb[(size_t)row*NC + c] = f2bf(accv);
      float s1 = accv * a1v[c];
      float s2 = accv * a2v[c];
      #pragma unroll
      for (int msk=1; msk<16; msk<<=1) { s1 += __shfl_xor(s1, msk); s2 += __shfl_xor(s2, msk); }
      if (c == 0) { f1out[row] = s1; f2out[row] = s2; }
    }
  } else {
    const int nit = (deg + 31) >> 5;
    float m = -1e30f;
    for (int it=0; it<nit; ++it) {
      const int idx = start + it*32 + lane;
      if (idx < end) {
        const int2 p = ldnt(&cvp[idx]);
        const float x = f1r + f2in[p.x];
        m = fmaxf(m, (x>0.f)?x:LEAKY*x);
      }
    }
    #pragma unroll
    for (int msk=1; msk<32; msk<<=1) m = fmaxf(m, __shfl_xor(m, msk));
    float s = 0.f;
    for (int it=0; it<nit; ++it) {
      const int idx = start + it*32 + lane;
      if (idx < end) {
        const int2 p = ldnt(&cvp[idx]);
        const float x = f1r + f2in[p.x];
        s += __expf(((x>0.f)?x:LEAKY*x) - m);
      }
    }
    #pragma unroll
    for (int msk=1; msk<32; msk<<=1) s += __shfl_xor(s, msk);
    const float lgs = LG / s;
    float a[16];
    #pragma unroll
    for (int k=0;k<16;++k) a[k]=0.f;
    for (int it=0; it<nit; ++it) {
      const int idx = start + it*32 + lane;
      if (idx < end) {
        const int2 p = ldnt(&cvp[idx]);
        const float x = f1r + f2in[p.x];
        const float coef = (1.f-LG)*__int_as_float(p.y) + __expf(((x>0.f)?x:LEAKY*x) - m)*lgs;
        const ushort_t* zp = Zb + (size_t)p.x*NC;
        #pragma unroll
        for (int k=0;k<16;++k) a[k] += coef * bf16f(zp[k]);
      }
    }
    #pragma unroll
    for (int msk=1; msk<32; msk<<=1) {
      #pragma unroll
      for (int k=0;k<16;++k) a[k] += __shfl_xor(a[k], msk);
    }
    if (lane == 0) {
      #pragma unroll
      for (int k=0;k<16;++k) Zoutb[(size_t)row*NC + k] = f2bf(a[k]);
      float s1=0.f, s2=0.f;
      #pragma unroll
      for (int k=0;k<16;++k) { s1 += a[k]*a1v[k]; s2 += a[k]*a2v[k]; }
      f1out[row]=s1; f2out[row]=s2;
    }
  }
}

// ---------------- hop 2 fused with the per-node 3-hop attention mix ----------------
__global__ __launch_bounds__(256) void k_hop2mix(const int* __restrict__ rowptr,
    const int2* __restrict__ cvp,
    const ushort_t* __restrict__ Z1b, const float* __restrict__ f1in,
    const float* __restrict__ f2in, const float* __restrict__ Z0,
    const float* __restrict__ Wat, float* __restrict__ outp)
{
  __shared__ __align__(16) int2 rowbuf[8][64];
  const int t = threadIdx.x;
  const int lane = t & 31;
  const int hw = t >> 5;
  const int row = blockIdx.x*8 + hw;
  if (row >= NN) return;
  const int start = rowptr[row], end = rowptr[row+1];
  const int deg = end - start;
  const int c = lane & 15, g = (lane >> 4) & 1;

  if (deg > 64) {
    const float f1r = f1in[row];
    const int nit = (deg + 31) >> 5;
    float m = -1e30f;
    for (int it=0; it<nit; ++it) {
      const int idx = start + it*32 + lane;
      if (idx < end) {
        const float x = f1r + f2in[ldnt(&cvp[idx]).x];
        m = fmaxf(m, (x>0.f)?x:LEAKY*x);
      }
    }
    #pragma unroll
    for (int msk=1; msk<32; msk<<=1) m = fmaxf(m, __shfl_xor(m, msk));
    float s = 0.f;
    for (int it=0; it<nit; ++it) {
      const int idx = start + it*32 + lane;
      if (idx < end) {
        const float x = f1r + f2in[ldnt(&cvp[idx]).x];
        s += __expf(((x>0.f)?x:LEAKY*x) - m);
      }
    }
    #pragma unroll
    for (int msk=1; msk<32; msk<<=1) s += __shfl_xor(s, msk);
    const float lgs = LG / s;
    float a[16];
    #pragma unroll
    for (int k=0;k<16;++k) a[k]=0.f;
    for (int it=0; it<nit; ++it) {
      const int idx = start + it*32 + lane;
      if (idx < end) {
        const int2 p = ldnt(&cvp[idx]);
        const float x = f1r + f2in[p.x];
        const float coef = (1.f-LG)*__int_as_float(p.y) + __expf(((x>0.f)?x:LEAKY*x) - m)*lgs;
        const ushort_t* zp = Z1b + (size_t)p.x*NC;
        #pragma unroll
        for (int k=0;k<16;++k) a[k] += coef * bf16f(zp[k]);
      }
    }
    #pragma unroll
    for (int msk=1; msk<32; msk<<=1) {
      #pragma unroll
      for (int k=0;k<16;++k) a[k] += __shfl_xor(a[k], msk);
    }
    if (lane == 0) {
      float t0=0.f, t1=0.f, t2=0.f;
      for (int k=0;k<16;++k) {
        const float w = Wat[(size_t)row*NC + k];
        t0 += Z0[(size_t)row*NC + k]*w;
        t1 += bf16f(Z1b[(size_t)row*NC + k])*w;
        t2 += a[k]*w;
      }
      const float mm = fmaxf(t0, fmaxf(t1, t2));
      const float q0 = __expf(t0-mm), q1 = __expf(t1-mm), q2 = __expf(t2-mm);
      const float inv = 1.f/(q0+q1+q2);
      for (int k=0;k<16;++k)
        outp[(size_t)row*NC + k] =
          (q0*Z0[(size_t)row*NC + k] + q1*bf16f(Z1b[(size_t)row*NC + k]) + q2*a[k])*inv;
    }
    return;
  }

  float accv = 0.f;
  if (deg > 0) {
    const float f1r = f1in[row];
    int cc0 = 0, cc1 = 0; float vv0 = 0.f, vv1 = 0.f;
    float e0 = -1e30f, e1 = -1e30f;
    if (lane < deg) {
      const int2 p = ldnt(&cvp[start + lane]);
      cc0 = p.x; vv0 = __int_as_float(p.y);
      const float x = f1r + f2in[cc0];
      e0 = (x > 0.f) ? x : LEAKY*x;
    }
    if (32 + lane < deg) {
      const int2 p = ldnt(&cvp[start + 32 + lane]);
      cc1 = p.x; vv1 = __int_as_float(p.y);
      const float x = f1r + f2in[cc1];
      e1 = (x > 0.f) ? x : LEAKY*x;
    }
    float m = fmaxf(e0, e1);
    #pragma unroll
    for (int msk=1; msk<32; msk<<=1) m = fmaxf(m, __shfl_xor(m, msk));
    const float ex0 = (lane < deg) ? __expf(e0 - m) : 0.f;
    const float ex1 = (32 + lane < deg) ? __expf(e1 - m) : 0.f;
    float s = ex0 + ex1;
    #pragma unroll
    for (int msk=1; msk<32; msk<<=1) s += __shfl_xor(s, msk);
    const float lgs = LG / s;
    const int npass = (deg + 3) >> 2;
    if (lane < deg)
      rowbuf[hw][lane] = make_int2(cc0, __float_as_int((1.f-LG)*vv0 + ex0*lgs));
    if (32 + lane < deg)
      rowbuf[hw][32 + lane] = make_int2(cc1, __float_as_int((1.f-LG)*vv1 + ex1*lgs));
    for (int z = deg + lane; z < 4*npass; z += 32) rowbuf[hw][z] = make_int2(0, 0);
    asm volatile("s_waitcnt lgkmcnt(0)" ::: "memory");
    for (int p0 = 0; p0 < npass; p0 += 8) {
      int4 pr[8]; ushort_t u0[8], u1[8];
      #pragma unroll
      for (int j=0;j<8;++j) {
        if (p0 + j < npass)
          pr[j] = *(const int4*)(&rowbuf[hw][(p0+j)*4 + g*2]);
        else
          pr[j] = make_int4(0, 0, 0, 0);
      }
      #pragma unroll
      for (int j=0;j<8;++j) {
        u0[j] = Z1b[(size_t)pr[j].x*NC + c];
        u1[j] = Z1b[(size_t)pr[j].z*NC + c];
      }
      #pragma unroll
      for (int j=0;j<8;++j) {
        accv += __int_as_float(pr[j].y) * bf16f(u0[j]);
        accv += __int_as_float(pr[j].w) * bf16f(u1[j]);
      }
    }
    accv += __shfl_xor(accv, 16);
  }
  if (g == 0) {
    const float z0v = Z0[(size_t)row*NC + c];
    const float z1v = bf16f(Z1b[(size_t)row*NC + c]);
    const float wv  = Wat[(size_t)row*NC + c];
    float t0 = z0v*wv, t1 = z1v*wv, t2 = accv*wv;
    #pragma unroll
    for (int msk=1; msk<16; msk<<=1) {
      t0 += __shfl_xor(t0, msk); t1 += __shfl_xor(t1, msk); t2 += __shfl_xor(t2, msk);
    }
    const float mm = fmaxf(t0, fmaxf(t1, t2));
    const float q0 = __expf(t0-mm), q1 = __expf(t1-mm), q2 = __expf(t2-mm);
    const float inv = 1.f/(q0+q1+q2);
    outp[(size_t)row*NC + c] = (q0*z0v + q1*z1v + q2*accv)*inv;
  }
}

extern "C" void kernel_launch(void* const* d_in, const int* in_sizes, int n_in,
                              void* d_out, int out_size, void* d_ws, size_t ws_size,
                              hipStream_t stream) {
  const float* X   = (const float*)d_in[0];
  const float* W0  = (const float*)d_in[1];
  const float* W1  = (const float*)d_in[2];
  const float* a1  = (const float*)d_in[3];
  const float* a2  = (const float*)d_in[4];
  const float* Wat = (const float*)d_in[5];
  const float* gcn = (const float*)d_in[6];
  const int*   ei  = (const int*)d_in[7];
  const int* src = ei;
  const int* dst = ei + NE;
  float* out = (float*)d_out;

  // workspace layout (element offsets; 16B alignment maintained)
  float* Z0      = (float*)d_ws;             // NN*NC f32 (for final mix)
  ushort_t* Z0b  = (ushort_t*)(Z0 + (size_t)NN*NC);  // NN*NC bf16 (hop1 gather table)
  ushort_t* Z1b  = Z0b + (size_t)NN*NC;      // NN*NC bf16 (hop2 gather table)
  float* fA1  = (float*)(Z1b + (size_t)NN*NC); // NN
  float* fA2  = fA1 + NN;                    // NN
  float* fB1  = fA2 + NN;                    // NN
  float* fB2  = fB1 + NN;                    // NN
  int* rowptr = (int*)(fB2 + NN);            // NN+4
  int* bcnt   = rowptr + (NN + 4);           // 256
  int* bbase  = bcnt + 256;                  // 256
  int* gcur   = bbase + 256;                 // 256
  int* done   = gcur + 256;                  // 4
  short* W0T  = (short*)(done + 4);          // 64*512 shorts (bf16 RNE)
  int2* cvp   = (int2*)(W0T + HIDN*FIN);     // NE int2 packed (col,val)
  int2* tmp   = cvp + NE;                    // NE int2 (dead after k_binB)

  k_w0t<<<(HIDN*FIN + 255)/256, 256, 0, stream>>>(W0, W0T, bcnt, done);
  k_mlp3<<<MLP_BLKS, 256, 0, stream>>>(X, W0T, W1, a1, a2, Z0, Z0b, fA1, fA2);
  k_bhist<<<BHIST_BLKS, 256, 0, stream>>>(src, bcnt, bbase, gcur, done);
  k_binA<<<(NE + TILE_A - 1)/TILE_A, 256, 0, stream>>>(src, dst, gcn, gcur, tmp);
  k_binB<<<NBUCK, 1024, 0, stream>>>(bbase, bcnt, tmp, rowptr, cvp);
  k_hop<<<12500, 256, 0, stream>>>(rowptr, cvp, Z0b, fA1, fA2, Z1b, fB1, fB2, a1, a2);
  k_hop2mix<<<12500, 256, 0, stream>>>(rowptr, cvp, Z1b, fB1, fB2, Z0, Wat, out);
}

// Round 14
// 271.272 us; speedup vs baseline: 1.1708x; 1.1708x over previous
//
#include <hip/hip_runtime.h>
#include <hip/hip_fp16.h>

#define NN 100000
#define NE 3200000
#define FIN 512
#define HIDN 64
#define NC 16
#define LEAKY 0.2f
#define LG 0.2f

// MFMA MLP params
#define GM 128        // rows per block (4 waves x 32 rows)
#define HLD2 72       // H row stride in LDS (bf16 shorts, 144B = 16B-aligned)
#define MLP_BLKS 782  // ceil(100000/128)

// bucket sort params
#define BSH 9                 // 512 nodes per bucket
#define NBUCK 196             // ceil(100000/512)
#define TILE_A 2048
#define SLACK 20480           // slack-allocated tmp region per bucket (mean 16327)

typedef float4 f4;
typedef short bf16x8 __attribute__((ext_vector_type(8)));
typedef float f32x4 __attribute__((ext_vector_type(4)));
typedef unsigned short ushort_t;

__device__ __forceinline__ bf16x8 cvt8(const f4 a, const f4 b) {
  union { unsigned u[4]; bf16x8 v; } o;
  asm("v_cvt_pk_bf16_f32 %0, %1, %2" : "=v"(o.u[0]) : "v"(a.x), "v"(a.y));
  asm("v_cvt_pk_bf16_f32 %0, %1, %2" : "=v"(o.u[1]) : "v"(a.z), "v"(a.w));
  asm("v_cvt_pk_bf16_f32 %0, %1, %2" : "=v"(o.u[2]) : "v"(b.x), "v"(b.y));
  asm("v_cvt_pk_bf16_f32 %0, %1, %2" : "=v"(o.u[3]) : "v"(b.z), "v"(b.w));
  return o.v;
}

__device__ __forceinline__ float bf16f(ushort_t s) {
  return __uint_as_float(((unsigned)s) << 16);
}
__device__ __forceinline__ ushort_t f2bf(float f) {
  const unsigned u = __float_as_uint(f);
  return (ushort_t)((u + 0x7fffu + ((u >> 16) & 1u)) >> 16);   // RNE
}
// non-temporal 8B load of an (int,int) pair
__device__ __forceinline__ int2 ldnt(const int2* p) {
  const int* q = (const int*)p;
  int2 r;
  r.x = __builtin_nontemporal_load(q);
  r.y = __builtin_nontemporal_load(q + 1);
  return r;
}

// ---------------- prep: W0 -> W0^T bf16; zeroes bcnt, inits slack cursors ----------------
__global__ __launch_bounds__(256) void k_w0t(const float* __restrict__ W0,
                                             short* __restrict__ W0T,
                                             int* __restrict__ bcnt,
                                             int* __restrict__ gcur) {
  const int i = blockIdx.x*256 + threadIdx.x;   // i = c*512 + k
  if (blockIdx.x == 0) {
    bcnt[threadIdx.x] = 0;                      // k_binA runs after us in-stream
    gcur[threadIdx.x] = threadIdx.x * SLACK;    // slack-region cursors
  }
  if (i >= HIDN*FIN) return;
  const int c = i >> 9, k = i & 511;
  W0T[i] = (short)f2bf(W0[(size_t)k*HIDN + c]);
}

// ---------------- MLP: Z = relu(X@W0)@W1 ; R11 version (64KB Wb, 2 blocks/CU) ----------------
__global__ __launch_bounds__(256, 2) void k_mlp3(
    const float* __restrict__ X, const short* __restrict__ W0T,
    const float* __restrict__ W1, const float* __restrict__ a1v,
    const float* __restrict__ a2v, float* __restrict__ Z,
    ushort_t* __restrict__ Zb, float* __restrict__ f1o, float* __restrict__ f2o)
{
  __shared__ __align__(16) char smem[HIDN*FIN*2];       // 64 KB total
  short* Wb = (short*)smem;                             // XOR-swizzled bf16 W^T (k-loop)
  short (*HsB)[HLD2] = (short(*)[HLD2])smem;            // aliased after k-loop
  float* W1s = (float*)(smem + GM*HLD2*2);              // 4 KB, after HsB region
  const int t = threadIdx.x;
  const int wid = t >> 6, lane = t & 63;
  const int r = lane & 15, g = lane >> 4;
  const int rowbase = blockIdx.x*GM + wid*32;
  int row0 = rowbase + r;       if (row0 >= NN) row0 = NN-1;
  int row1 = rowbase + 16 + r;  if (row1 >= NN) row1 = NN-1;
  const float* pa0 = X + (size_t)row0*FIN + g*8;
  const float* pa1 = X + (size_t)row1*FIN + g*8;

  f4 xs[4][2][2];
  #pragma unroll
  for (int d=0; d<4; ++d) {
    xs[d][0][0] = *(const f4*)(pa0 + d*32);  xs[d][0][1] = *(const f4*)(pa0 + d*32 + 4);
    xs[d][1][0] = *(const f4*)(pa1 + d*32);  xs[d][1][1] = *(const f4*)(pa1 + d*32 + 4);
  }

  #pragma unroll
  for (int i2 = 0; i2 < 16; ++i2) {
    const int i = t + i2*256;
    const int row = i >> 6;
    const int cb = (i & 63) << 4;
    const bf16x8 v = *(const bf16x8*)(W0T + (size_t)row*FIN + (i & 63)*8);
    *(bf16x8*)((char*)Wb + row*1024 + (cb ^ ((row & 7) << 4))) = v;
  }
  __syncthreads();

  f32x4 acc[2][4];
  #pragma unroll
  for (int m=0;m<2;++m)
    #pragma unroll
    for (int n=0;n<4;++n) acc[m][n] = (f32x4){0.f,0.f,0.f,0.f};

  #pragma unroll
  for (int ks=0; ks<16; ++ks) {
    const int st = ks & 3;
    bf16x8 bh[4];
    #pragma unroll
    for (int n=0;n<4;++n) {
      const int wrow = n*16 + r;
      const int boff = wrow*1024 + ((ks*64 + g*16) ^ ((wrow & 7) << 4));
      bh[n] = *(const bf16x8*)((const char*)Wb + boff);
    }
    const bf16x8 xb0 = cvt8(xs[st][0][0], xs[st][0][1]);
    const bf16x8 xb1 = cvt8(xs[st][1][0], xs[st][1][1]);
    if (ks + 4 < 16) {
      const int ko = (ks+4)*32;
      xs[st][0][0] = *(const f4*)(pa0 + ko);  xs[st][0][1] = *(const f4*)(pa0 + ko + 4);
      xs[st][1][0] = *(const f4*)(pa1 + ko);  xs[st][1][1] = *(const f4*)(pa1 + ko + 4);
    }
    #pragma unroll
    for (int n=0;n<4;++n) {
      acc[0][n] = __builtin_amdgcn_mfma_f32_16x16x32_bf16(xb0, bh[n], acc[0][n], 0,0,0);
      acc[1][n] = __builtin_amdgcn_mfma_f32_16x16x32_bf16(xb1, bh[n], acc[1][n], 0,0,0);
    }
  }
  __syncthreads();   // all waves done reading Wb before overwrite with H

  #pragma unroll
  for (int m=0;m<2;++m) {
    const int hr = wid*32 + m*16 + g*4;
    #pragma unroll
    for (int n=0;n<4;++n)
      #pragma unroll
      for (int q=0;q<4;++q)
        HsB[hr+q][n*16+r] = (short)f2bf(fmaxf(acc[m][n][q], 0.f));
  }
  *(f4*)(W1s + t*4) = *(const f4*)(W1 + t*4);
  __syncthreads();

  // layer 2: 2 threads per node; thread handles 8 channels
  {
    const int en = t >> 1, half = t & 1;
    const int node = blockIdx.x*GM + en;
    if (node < NN) {
      float z[8];
      #pragma unroll
      for (int j=0;j<8;++j) z[j]=0.f;
      const bf16x8* hp = (const bf16x8*)(&HsB[en][0]);
      #pragma unroll
      for (int h8=0; h8<8; ++h8) {
        const bf16x8 hv8 = hp[h8];
        #pragma unroll
        for (int j=0;j<8;++j) {
          const float hv = bf16f((ushort_t)hv8[j]);
          const int h = h8*8 + j;
          const f4 wa = *(const f4*)(W1s + h*NC + half*8);
          const f4 wb = *(const f4*)(W1s + h*NC + half*8 + 4);
          z[0]+=hv*wa.x; z[1]+=hv*wa.y; z[2]+=hv*wa.z; z[3]+=hv*wa.w;
          z[4]+=hv*wb.x; z[5]+=hv*wb.y; z[6]+=hv*wb.z; z[7]+=hv*wb.w;
        }
      }
      f4* zp = (f4*)(Z + (size_t)node*NC + half*8);
      zp[0] = make_float4(z[0],z[1],z[2],z[3]);
      zp[1] = make_float4(z[4],z[5],z[6],z[7]);
      bf16x8 zb;
      #pragma unroll
      for (int j=0;j<8;++j) zb[j] = (short)f2bf(z[j]);
      *(bf16x8*)(Zb + (size_t)node*NC + half*8) = zb;
      float s1=0.f, s2=0.f;
      #pragma unroll
      for (int j=0;j<8;++j) { s1 += z[j]*a1v[half*8+j]; s2 += z[j]*a2v[half*8+j]; }
      s1 += __shfl_xor(s1, 1);
      s2 += __shfl_xor(s2, 1);
      if (half == 0) { f1o[node] = s1; f2o[node] = s2; }
    }
  }
}

// ---------------- CSR build phase A: fused histogram + multi-split (slack regions) ----------------
__global__ __launch_bounds__(256) void k_binA(const int* __restrict__ src,
    const int* __restrict__ dst, const float* __restrict__ gcn,
    int* __restrict__ bcnt, int* __restrict__ gcur, int2* __restrict__ tmp)
{
  __shared__ int cnt[256];
  __shared__ int scn[256];
  __shared__ int cur[256];
  __shared__ int gbase[256];
  __shared__ int2 stage[TILE_A];
  __shared__ unsigned char sb[TILE_A];
  const int t = threadIdx.x;
  const int e0 = blockIdx.x*TILE_A;
  const int ecount = min(TILE_A, NE - e0);
  cnt[t] = 0;
  __syncthreads();
  int w0v[8], w1v[8], bv[8];
  #pragma unroll
  for (int it=0; it<8; ++it) {
    const int i = e0 + it*256 + t;
    bv[it] = -1;
    if (i < NE) {
      const int s_ = src[i];
      const int b = s_ >> BSH;
      bv[it] = b;
      w0v[it] = dst[i] | ((s_ & ((1<<BSH)-1)) << 17);
      w1v[it] = __float_as_int(gcn[i]);
      atomicAdd(&cnt[b], 1);
    }
  }
  __syncthreads();
  scn[t] = cnt[t];
  __syncthreads();
  for (int off=1; off<256; off<<=1) {
    const int x = (t>=off) ? scn[t-off] : 0;
    __syncthreads();
    scn[t] += x;
    __syncthreads();
  }
  cur[t] = scn[t] - cnt[t];
  if (cnt[t] > 0) {
    gbase[t] = atomicAdd(&gcur[t], cnt[t]);   // slack-region cursor (init t*SLACK)
    atomicAdd(&bcnt[t], cnt[t]);              // global per-bucket count
  }
  __syncthreads();
  #pragma unroll
  for (int it=0; it<8; ++it) {
    if (bv[it] >= 0) {
      const int pos = atomicAdd(&cur[bv[it]], 1);
      stage[pos] = make_int2(w0v[it], w1v[it]);
      sb[pos] = (unsigned char)bv[it];
    }
  }
  __syncthreads();
  #pragma unroll
  for (int it=0; it<8; ++it) {
    const int slot = it*256 + t;
    if (slot < ecount) {
      const int b = sb[slot];
      const int gd = gbase[b] + slot - (scn[b] - cnt[b]);
      tmp[gd] = stage[slot];
    }
  }
}

// ---------------- CSR build phase B: self-based fine sort -> packed (col,val) ----------------
__global__ __launch_bounds__(512) void k_binB(const int* __restrict__ bcnt,
    const int2* __restrict__ tmp, int* __restrict__ rowptr, int2* __restrict__ cvp)
{
  __shared__ int cnt[512];
  __shared__ int scn[512];
  __shared__ int cur[512];
  __shared__ int bs[256];
  __shared__ int baseSh;
  const int t = threadIdx.x;
  const int b = blockIdx.x;
  const int node0 = b << BSH;
  const int n = bcnt[b];
  const int2* tsl = tmp + (size_t)b*SLACK;
  // compute true CSR base: exclusive prefix of bcnt over buckets
  if (t < 256) bs[t] = (t < NBUCK) ? bcnt[t] : 0;
  cnt[t] = 0;
  __syncthreads();
  for (int off=1; off<256; off<<=1) {
    const int x = (t>=off && t<256) ? bs[t-off] : 0;
    __syncthreads();
    if (t < 256) bs[t] += x;
    __syncthreads();
  }
  if (t == 0) baseSh = bs[b] - n;
  __syncthreads();
  const int base = baseSh;
  // per-src histogram of this bucket
  for (int i = t; i < n; i += 512)
    atomicAdd(&cnt[tsl[i].x >> 17], 1);
  __syncthreads();
  scn[t] = cnt[t];
  __syncthreads();
  for (int off=1; off<512; off<<=1) {
    const int x = (t>=off) ? scn[t-off] : 0;
    __syncthreads();
    scn[t] += x;
    __syncthreads();
  }
  const int excl = scn[t] - cnt[t];
  cur[t] = excl;
  if (node0 + t < NN) rowptr[node0 + t] = base + excl;
  if (b == 0 && t == 0) rowptr[NN] = NE;
  __syncthreads();
  for (int i = t; i < n; i += 512) {
    const int2 e = tsl[i];
    const int ls = e.x >> 17;
    const int p = base + atomicAdd(&cur[ls], 1);
    cvp[p] = make_int2(e.x & 0x1FFFF, e.y);
  }
}

// ---------------- hop 1: bf16 L2 gathers, batched-issue PV pipeline ----------------
__global__ __launch_bounds__(256) void k_hop(const int* __restrict__ rowptr,
    const int2* __restrict__ cvp,
    const ushort_t* __restrict__ Zb, const float* __restrict__ f1in,
    const float* __restrict__ f2in, ushort_t* __restrict__ Zoutb,
    float* __restrict__ f1out, float* __restrict__ f2out,
    const float* __restrict__ a1v, const float* __restrict__ a2v)
{
  __shared__ __align__(16) int2 rowbuf[8][64];
  const int t = threadIdx.x;
  const int lane = t & 31;
  const int hw = t >> 5;
  const int row = blockIdx.x*8 + hw;
  if (row >= NN) return;
  const int start = rowptr[row], end = rowptr[row+1];
  const int deg = end - start;
  const int c = lane & 15, g = (lane >> 4) & 1;

  if (deg == 0) {
    if (g == 0) {
      Zoutb[(size_t)row*NC + c] = 0;
      if (c == 0) { f1out[row] = 0.f; f2out[row] = 0.f; }
    }
    return;
  }
  const float f1r = f1in[row];

  if (deg <= 64) {
    int cc0 = 0, cc1 = 0; float vv0 = 0.f, vv1 = 0.f;
    float e0 = -1e30f, e1 = -1e30f;
    if (lane < deg) {
      const int2 p = ldnt(&cvp[start + lane]);
      cc0 = p.x; vv0 = __int_as_float(p.y);
      const float x = f1r + f2in[cc0];
      e0 = (x > 0.f) ? x : LEAKY*x;
    }
    if (32 + lane < deg) {
      const int2 p = ldnt(&cvp[start + 32 + lane]);
      cc1 = p.x; vv1 = __int_as_float(p.y);
      const float x = f1r + f2in[cc1];
      e1 = (x > 0.f) ? x : LEAKY*x;
    }
    float m = fmaxf(e0, e1);
    #pragma unroll
    for (int msk=1; msk<32; msk<<=1) m = fmaxf(m, __shfl_xor(m, msk));
    const float ex0 = (lane < deg) ? __expf(e0 - m) : 0.f;
    const float ex1 = (32 + lane < deg) ? __expf(e1 - m) : 0.f;
    float s = ex0 + ex1;
    #pragma unroll
    for (int msk=1; msk<32; msk<<=1) s += __shfl_xor(s, msk);
    const float lgs = LG / s;
    const int npass = (deg + 3) >> 2;
    if (lane < deg)
      rowbuf[hw][lane] = make_int2(cc0, __float_as_int((1.f-LG)*vv0 + ex0*lgs));
    if (32 + lane < deg)
      rowbuf[hw][32 + lane] = make_int2(cc1, __float_as_int((1.f-LG)*vv1 + ex1*lgs));
    for (int z = deg + lane; z < 4*npass; z += 32) rowbuf[hw][z] = make_int2(0, 0);
    asm volatile("s_waitcnt lgkmcnt(0)" ::: "memory");
    float accv = 0.f;
    for (int p0 = 0; p0 < npass; p0 += 8) {
      int4 pr[8]; ushort_t u0[8], u1[8];
      #pragma unroll
      for (int j=0;j<8;++j) {
        if (p0 + j < npass)
          pr[j] = *(const int4*)(&rowbuf[hw][(p0+j)*4 + g*2]);
        else
          pr[j] = make_int4(0, 0, 0, 0);
      }
      #pragma unroll
      for (int j=0;j<8;++j) {
        u0[j] = Zb[(size_t)pr[j].x*NC + c];
        u1[j] = Zb[(size_t)pr[j].z*NC + c];
      }
      #pragma unroll
      for (int j=0;j<8;++j) {
        accv += __int_as_float(pr[j].y) * bf16f(u0[j]);
        accv += __int_as_float(pr[j].w) * bf16f(u1[j]);
      }
    }
    accv += __shfl_xor(accv, 16);
    if (g == 0) {
      Zoutb[(size_t)row*NC + c] = f2bf(accv);
      float s1 = accv * a1v[c];
      float s2 = accv * a2v[c];
      #pragma unroll
      for (int msk=1; msk<16; msk<<=1) { s1 += __shfl_xor(s1, msk); s2 += __shfl_xor(s2, msk); }
      if (c == 0) { f1out[row] = s1; f2out[row] = s2; }
    }
  } else {
    const int nit = (deg + 31) >> 5;
    float m = -1e30f;
    for (int it=0; it<nit; ++it) {
      const int idx = start + it*32 + lane;
      if (idx < end) {
        const int2 p = ldnt(&cvp[idx]);
        const float x = f1r + f2in[p.x];
        m = fmaxf(m, (x>0.f)?x:LEAKY*x);
      }
    }
    #pragma unroll
    for (int msk=1; msk<32; msk<<=1) m = fmaxf(m, __shfl_xor(m, msk));
    float s = 0.f;
    for (int it=0; it<nit; ++it) {
      const int idx = start + it*32 + lane;
      if (idx < end) {
        const int2 p = ldnt(&cvp[idx]);
        const float x = f1r + f2in[p.x];
        s += __expf(((x>0.f)?x:LEAKY*x) - m);
      }
    }
    #pragma unroll
    for (int msk=1; msk<32; msk<<=1) s += __shfl_xor(s, msk);
    const float lgs = LG / s;
    float a[16];
    #pragma unroll
    for (int k=0;k<16;++k) a[k]=0.f;
    for (int it=0; it<nit; ++it) {
      const int idx = start + it*32 + lane;
      if (idx < end) {
        const int2 p = ldnt(&cvp[idx]);
        const float x = f1r + f2in[p.x];
        const float coef = (1.f-LG)*__int_as_float(p.y) + __expf(((x>0.f)?x:LEAKY*x) - m)*lgs;
        const ushort_t* zp = Zb + (size_t)p.x*NC;
        #pragma unroll
        for (int k=0;k<16;++k) a[k] += coef * bf16f(zp[k]);
      }
    }
    #pragma unroll
    for (int msk=1; msk<32; msk<<=1) {
      #pragma unroll
      for (int k=0;k<16;++k) a[k] += __shfl_xor(a[k], msk);
    }
    if (lane == 0) {
      #pragma unroll
      for (int k=0;k<16;++k) Zoutb[(size_t)row*NC + k] = f2bf(a[k]);
      float s1=0.f, s2=0.f;
      #pragma unroll
      for (int k=0;k<16;++k) { s1 += a[k]*a1v[k]; s2 += a[k]*a2v[k]; }
      f1out[row]=s1; f2out[row]=s2;
    }
  }
}

// ---------------- hop 2 fused with the per-node 3-hop attention mix ----------------
__global__ __launch_bounds__(256) void k_hop2mix(const int* __restrict__ rowptr,
    const int2* __restrict__ cvp,
    const ushort_t* __restrict__ Z1b, const float* __restrict__ f1in,
    const float* __restrict__ f2in, const float* __restrict__ Z0,
    const float* __restrict__ Wat, float* __restrict__ outp)
{
  __shared__ __align__(16) int2 rowbuf[8][64];
  const int t = threadIdx.x;
  const int lane = t & 31;
  const int hw = t >> 5;
  const int row = blockIdx.x*8 + hw;
  if (row >= NN) return;
  const int start = rowptr[row], end = rowptr[row+1];
  const int deg = end - start;
  const int c = lane & 15, g = (lane >> 4) & 1;

  if (deg > 64) {
    const float f1r = f1in[row];
    const int nit = (deg + 31) >> 5;
    float m = -1e30f;
    for (int it=0; it<nit; ++it) {
      const int idx = start + it*32 + lane;
      if (idx < end) {
        const float x = f1r + f2in[ldnt(&cvp[idx]).x];
        m = fmaxf(m, (x>0.f)?x:LEAKY*x);
      }
    }
    #pragma unroll
    for (int msk=1; msk<32; msk<<=1) m = fmaxf(m, __shfl_xor(m, msk));
    float s = 0.f;
    for (int it=0; it<nit; ++it) {
      const int idx = start + it*32 + lane;
      if (idx < end) {
        const float x = f1r + f2in[ldnt(&cvp[idx]).x];
        s += __expf(((x>0.f)?x:LEAKY*x) - m);
      }
    }
    #pragma unroll
    for (int msk=1; msk<32; msk<<=1) s += __shfl_xor(s, msk);
    const float lgs = LG / s;
    float a[16];
    #pragma unroll
    for (int k=0;k<16;++k) a[k]=0.f;
    for (int it=0; it<nit; ++it) {
      const int idx = start + it*32 + lane;
      if (idx < end) {
        const int2 p = ldnt(&cvp[idx]);
        const float x = f1r + f2in[p.x];
        const float coef = (1.f-LG)*__int_as_float(p.y) + __expf(((x>0.f)?x:LEAKY*x) - m)*lgs;
        const ushort_t* zp = Z1b + (size_t)p.x*NC;
        #pragma unroll
        for (int k=0;k<16;++k) a[k] += coef * bf16f(zp[k]);
      }
    }
    #pragma unroll
    for (int msk=1; msk<32; msk<<=1) {
      #pragma unroll
      for (int k=0;k<16;++k) a[k] += __shfl_xor(a[k], msk);
    }
    if (lane == 0) {
      float t0=0.f, t1=0.f, t2=0.f;
      for (int k=0;k<16;++k) {
        const float w = Wat[(size_t)row*NC + k];
        t0 += Z0[(size_t)row*NC + k]*w;
        t1 += bf16f(Z1b[(size_t)row*NC + k])*w;
        t2 += a[k]*w;
      }
      const float mm = fmaxf(t0, fmaxf(t1, t2));
      const float q0 = __expf(t0-mm), q1 = __expf(t1-mm), q2 = __expf(t2-mm);
      const float inv = 1.f/(q0+q1+q2);
      for (int k=0;k<16;++k)
        outp[(size_t)row*NC + k] =
          (q0*Z0[(size_t)row*NC + k] + q1*bf16f(Z1b[(size_t)row*NC + k]) + q2*a[k])*inv;
    }
    return;
  }

  float accv = 0.f;
  if (deg > 0) {
    const float f1r = f1in[row];
    int cc0 = 0, cc1 = 0; float vv0 = 0.f, vv1 = 0.f;
    float e0 = -1e30f, e1 = -1e30f;
    if (lane < deg) {
      const int2 p = ldnt(&cvp[start + lane]);
      cc0 = p.x; vv0 = __int_as_float(p.y);
      const float x = f1r + f2in[cc0];
      e0 = (x > 0.f) ? x : LEAKY*x;
    }
    if (32 + lane < deg) {
      const int2 p = ldnt(&cvp[start + 32 + lane]);
      cc1 = p.x; vv1 = __int_as_float(p.y);
      const float x = f1r + f2in[cc1];
      e1 = (x > 0.f) ? x : LEAKY*x;
    }
    float m = fmaxf(e0, e1);
    #pragma unroll
    for (int msk=1; msk<32; msk<<=1) m = fmaxf(m, __shfl_xor(m, msk));
    const float ex0 = (lane < deg) ? __expf(e0 - m) : 0.f;
    const float ex1 = (32 + lane < deg) ? __expf(e1 - m) : 0.f;
    float s = ex0 + ex1;
    #pragma unroll
    for (int msk=1; msk<32; msk<<=1) s += __shfl_xor(s, msk);
    const float lgs = LG / s;
    const int npass = (deg + 3) >> 2;
    if (lane < deg)
      rowbuf[hw][lane] = make_int2(cc0, __float_as_int((1.f-LG)*vv0 + ex0*lgs));
    if (32 + lane < deg)
      rowbuf[hw][32 + lane] = make_int2(cc1, __float_as_int((1.f-LG)*vv1 + ex1*lgs));
    for (int z = deg + lane; z < 4*npass; z += 32) rowbuf[hw][z] = make_int2(0, 0);
    asm volatile("s_waitcnt lgkmcnt(0)" ::: "memory");
    for (int p0 = 0; p0 < npass; p0 += 8) {
      int4 pr[8]; ushort_t u0[8], u1[8];
      #pragma unroll
      for (int j=0;j<8;++j) {
        if (p0 + j < npass)
          pr[j] = *(const int4*)(&rowbuf[hw][(p0+j)*4 + g*2]);
        else
          pr[j] = make_int4(0, 0, 0, 0);
      }
      #pragma unroll
      for (int j=0;j<8;++j) {
        u0[j] = Z1b[(size_t)pr[j].x*NC + c];
        u1[j] = Z1b[(size_t)pr[j].z*NC + c];
      }
      #pragma unroll
      for (int j=0;j<8;++j) {
        accv += __int_as_float(pr[j].y) * bf16f(u0[j]);
        accv += __int_as_float(pr[j].w) * bf16f(u1[j]);
      }
    }
    accv += __shfl_xor(accv, 16);
  }
  if (g == 0) {
    const float z0v = Z0[(size_t)row*NC + c];
    const float z1v = bf16f(Z1b[(size_t)row*NC + c]);
    const float wv  = Wat[(size_t)row*NC + c];
    float t0 = z0v*wv, t1 = z1v*wv, t2 = accv*wv;
    #pragma unroll
    for (int msk=1; msk<16; msk<<=1) {
      t0 += __shfl_xor(t0, msk); t1 += __shfl_xor(t1, msk); t2 += __shfl_xor(t2, msk);
    }
    const float mm = fmaxf(t0, fmaxf(t1, t2));
    const float q0 = __expf(t0-mm), q1 = __expf(t1-mm), q2 = __expf(t2-mm);
    const float inv = 1.f/(q0+q1+q2);
    outp[(size_t)row*NC + c] = (q0*z0v + q1*z1v + q2*accv)*inv;
  }
}

extern "C" void kernel_launch(void* const* d_in, const int* in_sizes, int n_in,
                              void* d_out, int out_size, void* d_ws, size_t ws_size,
                              hipStream_t stream) {
  const float* X   = (const float*)d_in[0];
  const float* W0  = (const float*)d_in[1];
  const float* W1  = (const float*)d_in[2];
  const float* a1  = (const float*)d_in[3];
  const float* a2  = (const float*)d_in[4];
  const float* Wat = (const float*)d_in[5];
  const float* gcn = (const float*)d_in[6];
  const int*   ei  = (const int*)d_in[7];
  const int* src = ei;
  const int* dst = ei + NE;
  float* out = (float*)d_out;

  // workspace layout (element offsets; 16B alignment maintained)
  float* Z0      = (float*)d_ws;             // NN*NC f32 (for final mix)
  ushort_t* Z0b  = (ushort_t*)(Z0 + (size_t)NN*NC);  // NN*NC bf16 (hop1 gather table)
  ushort_t* Z1b  = Z0b + (size_t)NN*NC;      // NN*NC bf16 (hop2 gather table)
  float* fA1  = (float*)(Z1b + (size_t)NN*NC); // NN
  float* fA2  = fA1 + NN;                    // NN
  float* fB1  = fA2 + NN;                    // NN
  float* fB2  = fB1 + NN;                    // NN
  int* rowptr = (int*)(fB2 + NN);            // NN+4
  int* bcnt   = rowptr + (NN + 4);           // 256
  int* gcur   = bcnt + 256;                  // 256
  short* W0T  = (short*)(gcur + 256);        // 64*512 shorts (bf16 RNE)
  int2* cvp   = (int2*)(W0T + HIDN*FIN);     // NE int2 packed (col,val)
  int2* tmp   = cvp + NE;                    // NBUCK*SLACK int2 (dead after k_binB)

  k_w0t<<<(HIDN*FIN + 255)/256, 256, 0, stream>>>(W0, W0T, bcnt, gcur);
  k_mlp3<<<MLP_BLKS, 256, 0, stream>>>(X, W0T, W1, a1, a2, Z0, Z0b, fA1, fA2);
  k_binA<<<(NE + TILE_A - 1)/TILE_A, 256, 0, stream>>>(src, dst, gcn, bcnt, gcur, tmp);
  k_binB<<<NBUCK, 512, 0, stream>>>(bcnt, tmp, rowptr, cvp);
  k_hop<<<12500, 256, 0, stream>>>(rowptr, cvp, Z0b, fA1, fA2, Z1b, fB1, fB2, a1, a2);
  k_hop2mix<<<12500, 256, 0, stream>>>(rowptr, cvp, Z1b, fB1, fB2, Z0, Wat, out);
}

// Round 15
// 235.608 us; speedup vs baseline: 1.3480x; 1.1514x over previous
//
#include <hip/hip_runtime.h>
#include <hip/hip_fp16.h>

#define NN 100000
#define NE 3200000
#define FIN 512
#define HIDN 64
#define NC 16
#define LEAKY 0.2f
#define LG 0.2f

// MFMA MLP params
#define GM 128        // rows per block (4 waves x 32 rows)
#define HLD2 72       // H row stride in LDS (bf16 shorts, 144B = 16B-aligned)
#define MLP_BLKS 782  // ceil(100000/128)

// bucket sort params
#define BSH 9                 // 512 nodes per bucket
#define NBUCK 196             // ceil(100000/512)
#define TILE_A 4096           // edges per binA block (512 threads x 8)
#define SLACK 20480           // slack-allocated tmp region per bucket (mean 16327)

typedef float4 f4;
typedef short bf16x8 __attribute__((ext_vector_type(8)));
typedef float f32x4 __attribute__((ext_vector_type(4)));
typedef unsigned short ushort_t;

__device__ __forceinline__ bf16x8 cvt8(const f4 a, const f4 b) {
  union { unsigned u[4]; bf16x8 v; } o;
  asm("v_cvt_pk_bf16_f32 %0, %1, %2" : "=v"(o.u[0]) : "v"(a.x), "v"(a.y));
  asm("v_cvt_pk_bf16_f32 %0, %1, %2" : "=v"(o.u[1]) : "v"(a.z), "v"(a.w));
  asm("v_cvt_pk_bf16_f32 %0, %1, %2" : "=v"(o.u[2]) : "v"(b.x), "v"(b.y));
  asm("v_cvt_pk_bf16_f32 %0, %1, %2" : "=v"(o.u[3]) : "v"(b.z), "v"(b.w));
  return o.v;
}

__device__ __forceinline__ float bf16f(ushort_t s) {
  return __uint_as_float(((unsigned)s) << 16);
}
__device__ __forceinline__ ushort_t f2bf(float f) {
  const unsigned u = __float_as_uint(f);
  return (ushort_t)((u + 0x7fffu + ((u >> 16) & 1u)) >> 16);   // RNE
}
// non-temporal 8B load of an (int,int) pair
__device__ __forceinline__ int2 ldnt(const int2* p) {
  const int* q = (const int*)p;
  int2 r;
  r.x = __builtin_nontemporal_load(q);
  r.y = __builtin_nontemporal_load(q + 1);
  return r;
}

// ---------------- prep: W0 -> W0^T bf16; zeroes bcnt, inits slack cursors ----------------
__global__ __launch_bounds__(256) void k_w0t(const float* __restrict__ W0,
                                             short* __restrict__ W0T,
                                             int* __restrict__ bcnt,
                                             int* __restrict__ gcur) {
  const int i = blockIdx.x*256 + threadIdx.x;   // i = c*512 + k
  if (blockIdx.x == 0) {
    bcnt[threadIdx.x] = 0;                      // k_binA runs after us in-stream
    gcur[threadIdx.x] = threadIdx.x * SLACK;    // slack-region cursors
  }
  if (i >= HIDN*FIN) return;
  const int c = i >> 9, k = i & 511;
  W0T[i] = (short)f2bf(W0[(size_t)k*HIDN + c]);
}

// ---------------- MLP: Z = relu(X@W0)@W1 ; R11 version (64KB Wb, 2 blocks/CU) ----------------
__global__ __launch_bounds__(256, 2) void k_mlp3(
    const float* __restrict__ X, const short* __restrict__ W0T,
    const float* __restrict__ W1, const float* __restrict__ a1v,
    const float* __restrict__ a2v, float* __restrict__ Z,
    ushort_t* __restrict__ Zb, float* __restrict__ f1o, float* __restrict__ f2o)
{
  __shared__ __align__(16) char smem[HIDN*FIN*2];       // 64 KB total
  short* Wb = (short*)smem;                             // XOR-swizzled bf16 W^T (k-loop)
  short (*HsB)[HLD2] = (short(*)[HLD2])smem;            // aliased after k-loop
  float* W1s = (float*)(smem + GM*HLD2*2);              // 4 KB, after HsB region
  const int t = threadIdx.x;
  const int wid = t >> 6, lane = t & 63;
  const int r = lane & 15, g = lane >> 4;
  const int rowbase = blockIdx.x*GM + wid*32;
  int row0 = rowbase + r;       if (row0 >= NN) row0 = NN-1;
  int row1 = rowbase + 16 + r;  if (row1 >= NN) row1 = NN-1;
  const float* pa0 = X + (size_t)row0*FIN + g*8;
  const float* pa1 = X + (size_t)row1*FIN + g*8;

  f4 xs[4][2][2];
  #pragma unroll
  for (int d=0; d<4; ++d) {
    xs[d][0][0] = *(const f4*)(pa0 + d*32);  xs[d][0][1] = *(const f4*)(pa0 + d*32 + 4);
    xs[d][1][0] = *(const f4*)(pa1 + d*32);  xs[d][1][1] = *(const f4*)(pa1 + d*32 + 4);
  }

  #pragma unroll
  for (int i2 = 0; i2 < 16; ++i2) {
    const int i = t + i2*256;
    const int row = i >> 6;
    const int cb = (i & 63) << 4;
    const bf16x8 v = *(const bf16x8*)(W0T + (size_t)row*FIN + (i & 63)*8);
    *(bf16x8*)((char*)Wb + row*1024 + (cb ^ ((row & 7) << 4))) = v;
  }
  __syncthreads();

  f32x4 acc[2][4];
  #pragma unroll
  for (int m=0;m<2;++m)
    #pragma unroll
    for (int n=0;n<4;++n) acc[m][n] = (f32x4){0.f,0.f,0.f,0.f};

  #pragma unroll
  for (int ks=0; ks<16; ++ks) {
    const int st = ks & 3;
    bf16x8 bh[4];
    #pragma unroll
    for (int n=0;n<4;++n) {
      const int wrow = n*16 + r;
      const int boff = wrow*1024 + ((ks*64 + g*16) ^ ((wrow & 7) << 4));
      bh[n] = *(const bf16x8*)((const char*)Wb + boff);
    }
    const bf16x8 xb0 = cvt8(xs[st][0][0], xs[st][0][1]);
    const bf16x8 xb1 = cvt8(xs[st][1][0], xs[st][1][1]);
    if (ks + 4 < 16) {
      const int ko = (ks+4)*32;
      xs[st][0][0] = *(const f4*)(pa0 + ko);  xs[st][0][1] = *(const f4*)(pa0 + ko + 4);
      xs[st][1][0] = *(const f4*)(pa1 + ko);  xs[st][1][1] = *(const f4*)(pa1 + ko + 4);
    }
    #pragma unroll
    for (int n=0;n<4;++n) {
      acc[0][n] = __builtin_amdgcn_mfma_f32_16x16x32_bf16(xb0, bh[n], acc[0][n], 0,0,0);
      acc[1][n] = __builtin_amdgcn_mfma_f32_16x16x32_bf16(xb1, bh[n], acc[1][n], 0,0,0);
    }
  }
  __syncthreads();   // all waves done reading Wb before overwrite with H

  #pragma unroll
  for (int m=0;m<2;++m) {
    const int hr = wid*32 + m*16 + g*4;
    #pragma unroll
    for (int n=0;n<4;++n)
      #pragma unroll
      for (int q=0;q<4;++q)
        HsB[hr+q][n*16+r] = (short)f2bf(fmaxf(acc[m][n][q], 0.f));
  }
  *(f4*)(W1s + t*4) = *(const f4*)(W1 + t*4);
  __syncthreads();

  // layer 2: 2 threads per node; thread handles 8 channels
  {
    const int en = t >> 1, half = t & 1;
    const int node = blockIdx.x*GM + en;
    if (node < NN) {
      float z[8];
      #pragma unroll
      for (int j=0;j<8;++j) z[j]=0.f;
      const bf16x8* hp = (const bf16x8*)(&HsB[en][0]);
      #pragma unroll
      for (int h8=0; h8<8; ++h8) {
        const bf16x8 hv8 = hp[h8];
        #pragma unroll
        for (int j=0;j<8;++j) {
          const float hv = bf16f((ushort_t)hv8[j]);
          const int h = h8*8 + j;
          const f4 wa = *(const f4*)(W1s + h*NC + half*8);
          const f4 wb = *(const f4*)(W1s + h*NC + half*8 + 4);
          z[0]+=hv*wa.x; z[1]+=hv*wa.y; z[2]+=hv*wa.z; z[3]+=hv*wa.w;
          z[4]+=hv*wb.x; z[5]+=hv*wb.y; z[6]+=hv*wb.z; z[7]+=hv*wb.w;
        }
      }
      f4* zp = (f4*)(Z + (size_t)node*NC + half*8);
      zp[0] = make_float4(z[0],z[1],z[2],z[3]);
      zp[1] = make_float4(z[4],z[5],z[6],z[7]);
      bf16x8 zb;
      #pragma unroll
      for (int j=0;j<8;++j) zb[j] = (short)f2bf(z[j]);
      *(bf16x8*)(Zb + (size_t)node*NC + half*8) = zb;
      float s1=0.f, s2=0.f;
      #pragma unroll
      for (int j=0;j<8;++j) { s1 += z[j]*a1v[half*8+j]; s2 += z[j]*a2v[half*8+j]; }
      s1 += __shfl_xor(s1, 1);
      s2 += __shfl_xor(s2, 1);
      if (half == 0) { f1o[node] = s1; f2o[node] = s2; }
    }
  }
}

// ---------------- CSR build phase A: fused histogram + multi-split (slack regions) ----------------
// 512 threads x 4096-edge tiles: half the scan/barrier overhead, 2x longer write runs
__global__ __launch_bounds__(512) void k_binA(const int* __restrict__ src,
    const int* __restrict__ dst, const float* __restrict__ gcn,
    int* __restrict__ bcnt, int* __restrict__ gcur, int2* __restrict__ tmp)
{
  __shared__ int cnt[256];
  __shared__ int scn[256];
  __shared__ int cur[256];
  __shared__ int gbase[256];
  __shared__ int2 stage[TILE_A];
  __shared__ unsigned char sb[TILE_A];
  const int t = threadIdx.x;
  const int e0 = blockIdx.x*TILE_A;
  const int ecount = min(TILE_A, NE - e0);
  if (t < 256) cnt[t] = 0;
  __syncthreads();
  int w0v[8], w1v[8], bv[8];
  #pragma unroll
  for (int it=0; it<8; ++it) {
    const int i = e0 + it*512 + t;
    bv[it] = -1;
    if (i < NE) {
      const int s_ = src[i];
      const int b = s_ >> BSH;
      bv[it] = b;
      w0v[it] = dst[i] | ((s_ & ((1<<BSH)-1)) << 17);
      w1v[it] = __float_as_int(gcn[i]);
      atomicAdd(&cnt[b], 1);
    }
  }
  __syncthreads();
  if (t < 256) scn[t] = cnt[t];
  __syncthreads();
  for (int off=1; off<256; off<<=1) {
    const int x = (t>=off && t<256) ? scn[t-off] : 0;
    __syncthreads();
    if (t < 256) scn[t] += x;
    __syncthreads();
  }
  if (t < 256) {
    cur[t] = scn[t] - cnt[t];
    if (cnt[t] > 0) {
      gbase[t] = atomicAdd(&gcur[t], cnt[t]);   // slack-region cursor (init t*SLACK)
      atomicAdd(&bcnt[t], cnt[t]);              // global per-bucket count
    }
  }
  __syncthreads();
  #pragma unroll
  for (int it=0; it<8; ++it) {
    if (bv[it] >= 0) {
      const int pos = atomicAdd(&cur[bv[it]], 1);
      stage[pos] = make_int2(w0v[it], w1v[it]);
      sb[pos] = (unsigned char)bv[it];
    }
  }
  __syncthreads();
  #pragma unroll
  for (int it=0; it<8; ++it) {
    const int slot = it*512 + t;
    if (slot < ecount) {
      const int b = sb[slot];
      const int gd = gbase[b] + slot - (scn[b] - cnt[b]);
      tmp[gd] = stage[slot];
    }
  }
}

// ---------------- CSR build phase B: self-based fine sort -> packed (col,val) ----------------
__global__ __launch_bounds__(512) void k_binB(const int* __restrict__ bcnt,
    const int2* __restrict__ tmp, int* __restrict__ rowptr, int2* __restrict__ cvp)
{
  __shared__ int cnt[512];
  __shared__ int scn[512];
  __shared__ int cur[512];
  __shared__ int bs[256];
  __shared__ int baseSh;
  const int t = threadIdx.x;
  const int b = blockIdx.x;
  const int node0 = b << BSH;
  const int n = bcnt[b];
  const int2* tsl = tmp + (size_t)b*SLACK;
  // compute true CSR base: exclusive prefix of bcnt over buckets
  if (t < 256) bs[t] = (t < NBUCK) ? bcnt[t] : 0;
  cnt[t] = 0;
  __syncthreads();
  for (int off=1; off<256; off<<=1) {
    const int x = (t>=off && t<256) ? bs[t-off] : 0;
    __syncthreads();
    if (t < 256) bs[t] += x;
    __syncthreads();
  }
  if (t == 0) baseSh = bs[b] - n;
  __syncthreads();
  const int base = baseSh;
  // per-src histogram of this bucket
  for (int i = t; i < n; i += 512)
    atomicAdd(&cnt[tsl[i].x >> 17], 1);
  __syncthreads();
  scn[t] = cnt[t];
  __syncthreads();
  for (int off=1; off<512; off<<=1) {
    const int x = (t>=off) ? scn[t-off] : 0;
    __syncthreads();
    scn[t] += x;
    __syncthreads();
  }
  const int excl = scn[t] - cnt[t];
  cur[t] = excl;
  if (node0 + t < NN) rowptr[node0 + t] = base + excl;
  if (b == 0 && t == 0) rowptr[NN] = NE;
  __syncthreads();
  for (int i = t; i < n; i += 512) {
    const int2 e = tsl[i];
    const int ls = e.x >> 17;
    const int p = base + atomicAdd(&cur[ls], 1);
    cvp[p] = make_int2(e.x & 0x1FFFF, e.y);
  }
}

// ---------------- hop 1: bf16 L2 gathers, batched-issue PV pipeline ----------------
__global__ __launch_bounds__(256) void k_hop(const int* __restrict__ rowptr,
    const int2* __restrict__ cvp,
    const ushort_t* __restrict__ Zb, const float* __restrict__ f1in,
    const float* __restrict__ f2in, ushort_t* __restrict__ Zoutb,
    float* __restrict__ f1out, float* __restrict__ f2out,
    const float* __restrict__ a1v, const float* __restrict__ a2v)
{
  __shared__ __align__(16) int2 rowbuf[8][64];
  const int t = threadIdx.x;
  const int lane = t & 31;
  const int hw = t >> 5;
  const int row = blockIdx.x*8 + hw;
  if (row >= NN) return;
  const int start = rowptr[row], end = rowptr[row+1];
  const int deg = end - start;
  const int c = lane & 15, g = (lane >> 4) & 1;

  if (deg == 0) {
    if (g == 0) {
      Zoutb[(size_t)row*NC + c] = 0;
      if (c == 0) { f1out[row] = 0.f; f2out[row] = 0.f; }
    }
    return;
  }
  const float f1r = f1in[row];

  if (deg <= 64) {
    int cc0 = 0, cc1 = 0; float vv0 = 0.f, vv1 = 0.f;
    float e0 = -1e30f, e1 = -1e30f;
    if (lane < deg) {
      const int2 p = ldnt(&cvp[start + lane]);
      cc0 = p.x; vv0 = __int_as_float(p.y);
      const float x = f1r + f2in[cc0];
      e0 = (x > 0.f) ? x : LEAKY*x;
    }
    if (32 + lane < deg) {
      const int2 p = ldnt(&cvp[start + 32 + lane]);
      cc1 = p.x; vv1 = __int_as_float(p.y);
      const float x = f1r + f2in[cc1];
      e1 = (x > 0.f) ? x : LEAKY*x;
    }
    float m = fmaxf(e0, e1);
    #pragma unroll
    for (int msk=1; msk<32; msk<<=1) m = fmaxf(m, __shfl_xor(m, msk));
    const float ex0 = (lane < deg) ? __expf(e0 - m) : 0.f;
    const float ex1 = (32 + lane < deg) ? __expf(e1 - m) : 0.f;
    float s = ex0 + ex1;
    #pragma unroll
    for (int msk=1; msk<32; msk<<=1) s += __shfl_xor(s, msk);
    const float lgs = LG / s;
    const int npass = (deg + 3) >> 2;
    if (lane < deg)
      rowbuf[hw][lane] = make_int2(cc0, __float_as_int((1.f-LG)*vv0 + ex0*lgs));
    if (32 + lane < deg)
      rowbuf[hw][32 + lane] = make_int2(cc1, __float_as_int((1.f-LG)*vv1 + ex1*lgs));
    for (int z = deg + lane; z < 4*npass; z += 32) rowbuf[hw][z] = make_int2(0, 0);
    asm volatile("s_waitcnt lgkmcnt(0)" ::: "memory");
    float accv = 0.f;
    for (int p0 = 0; p0 < npass; p0 += 8) {
      int4 pr[8]; ushort_t u0[8], u1[8];
      #pragma unroll
      for (int j=0;j<8;++j) {
        if (p0 + j < npass)
          pr[j] = *(const int4*)(&rowbuf[hw][(p0+j)*4 + g*2]);
        else
          pr[j] = make_int4(0, 0, 0, 0);
      }
      #pragma unroll
      for (int j=0;j<8;++j) {
        u0[j] = Zb[(size_t)pr[j].x*NC + c];
        u1[j] = Zb[(size_t)pr[j].z*NC + c];
      }
      #pragma unroll
      for (int j=0;j<8;++j) {
        accv += __int_as_float(pr[j].y) * bf16f(u0[j]);
        accv += __int_as_float(pr[j].w) * bf16f(u1[j]);
      }
    }
    accv += __shfl_xor(accv, 16);
    if (g == 0) {
      Zoutb[(size_t)row*NC + c] = f2bf(accv);
      float s1 = accv * a1v[c];
      float s2 = accv * a2v[c];
      #pragma unroll
      for (int msk=1; msk<16; msk<<=1) { s1 += __shfl_xor(s1, msk); s2 += __shfl_xor(s2, msk); }
      if (c == 0) { f1out[row] = s1; f2out[row] = s2; }
    }
  } else {
    const int nit = (deg + 31) >> 5;
    float m = -1e30f;
    for (int it=0; it<nit; ++it) {
      const int idx = start + it*32 + lane;
      if (idx < end) {
        const int2 p = ldnt(&cvp[idx]);
        const float x = f1r + f2in[p.x];
        m = fmaxf(m, (x>0.f)?x:LEAKY*x);
      }
    }
    #pragma unroll
    for (int msk=1; msk<32; msk<<=1) m = fmaxf(m, __shfl_xor(m, msk));
    float s = 0.f;
    for (int it=0; it<nit; ++it) {
      const int idx = start + it*32 + lane;
      if (idx < end) {
        const int2 p = ldnt(&cvp[idx]);
        const float x = f1r + f2in[p.x];
        s += __expf(((x>0.f)?x:LEAKY*x) - m);
      }
    }
    #pragma unroll
    for (int msk=1; msk<32; msk<<=1) s += __shfl_xor(s, msk);
    const float lgs = LG / s;
    float a[16];
    #pragma unroll
    for (int k=0;k<16;++k) a[k]=0.f;
    for (int it=0; it<nit; ++it) {
      const int idx = start + it*32 + lane;
      if (idx < end) {
        const int2 p = ldnt(&cvp[idx]);
        const float x = f1r + f2in[p.x];
        const float coef = (1.f-LG)*__int_as_float(p.y) + __expf(((x>0.f)?x:LEAKY*x) - m)*lgs;
        const ushort_t* zp = Zb + (size_t)p.x*NC;
        #pragma unroll
        for (int k=0;k<16;++k) a[k] += coef * bf16f(zp[k]);
      }
    }
    #pragma unroll
    for (int msk=1; msk<32; msk<<=1) {
      #pragma unroll
      for (int k=0;k<16;++k) a[k] += __shfl_xor(a[k], msk);
    }
    if (lane == 0) {
      #pragma unroll
      for (int k=0;k<16;++k) Zoutb[(size_t)row*NC + k] = f2bf(a[k]);
      float s1=0.f, s2=0.f;
      #pragma unroll
      for (int k=0;k<16;++k) { s1 += a[k]*a1v[k]; s2 += a[k]*a2v[k]; }
      f1out[row]=s1; f2out[row]=s2;
    }
  }
}

// ---------------- hop 2 fused with the per-node 3-hop attention mix ----------------
__global__ __launch_bounds__(256) void k_hop2mix(const int* __restrict__ rowptr,
    const int2* __restrict__ cvp,
    const ushort_t* __restrict__ Z1b, const float* __restrict__ f1in,
    const float* __restrict__ f2in, const float* __restrict__ Z0,
    const float* __restrict__ Wat, float* __restrict__ outp)
{
  __shared__ __align__(16) int2 rowbuf[8][64];
  const int t = threadIdx.x;
  const int lane = t & 31;
  const int hw = t >> 5;
  const int row = blockIdx.x*8 + hw;
  if (row >= NN) return;
  const int start = rowptr[row], end = rowptr[row+1];
  const int deg = end - start;
  const int c = lane & 15, g = (lane >> 4) & 1;

  if (deg > 64) {
    const float f1r = f1in[row];
    const int nit = (deg + 31) >> 5;
    float m = -1e30f;
    for (int it=0; it<nit; ++it) {
      const int idx = start + it*32 + lane;
      if (idx < end) {
        const float x = f1r + f2in[ldnt(&cvp[idx]).x];
        m = fmaxf(m, (x>0.f)?x:LEAKY*x);
      }
    }
    #pragma unroll
    for (int msk=1; msk<32; msk<<=1) m = fmaxf(m, __shfl_xor(m, msk));
    float s = 0.f;
    for (int it=0; it<nit; ++it) {
      const int idx = start + it*32 + lane;
      if (idx < end) {
        const float x = f1r + f2in[ldnt(&cvp[idx]).x];
        s += __expf(((x>0.f)?x:LEAKY*x) - m);
      }
    }
    #pragma unroll
    for (int msk=1; msk<32; msk<<=1) s += __shfl_xor(s, msk);
    const float lgs = LG / s;
    float a[16];
    #pragma unroll
    for (int k=0;k<16;++k) a[k]=0.f;
    for (int it=0; it<nit; ++it) {
      const int idx = start + it*32 + lane;
      if (idx < end) {
        const int2 p = ldnt(&cvp[idx]);
        const float x = f1r + f2in[p.x];
        const float coef = (1.f-LG)*__int_as_float(p.y) + __expf(((x>0.f)?x:LEAKY*x) - m)*lgs;
        const ushort_t* zp = Z1b + (size_t)p.x*NC;
        #pragma unroll
        for (int k=0;k<16;++k) a[k] += coef * bf16f(zp[k]);
      }
    }
    #pragma unroll
    for (int msk=1; msk<32; msk<<=1) {
      #pragma unroll
      for (int k=0;k<16;++k) a[k] += __shfl_xor(a[k], msk);
    }
    if (lane == 0) {
      float t0=0.f, t1=0.f, t2=0.f;
      for (int k=0;k<16;++k) {
        const float w = Wat[(size_t)row*NC + k];
        t0 += Z0[(size_t)row*NC + k]*w;
        t1 += bf16f(Z1b[(size_t)row*NC + k])*w;
        t2 += a[k]*w;
      }
      const float mm = fmaxf(t0, fmaxf(t1, t2));
      const float q0 = __expf(t0-mm), q1 = __expf(t1-mm), q2 = __expf(t2-mm);
      const float inv = 1.f/(q0+q1+q2);
      for (int k=0;k<16;++k)
        outp[(size_t)row*NC + k] =
          (q0*Z0[(size_t)row*NC + k] + q1*bf16f(Z1b[(size_t)row*NC + k]) + q2*a[k])*inv;
    }
    return;
  }

  float accv = 0.f;
  if (deg > 0) {
    const float f1r = f1in[row];
    int cc0 = 0, cc1 = 0; float vv0 = 0.f, vv1 = 0.f;
    float e0 = -1e30f, e1 = -1e30f;
    if (lane < deg) {
      const int2 p = ldnt(&cvp[start + lane]);
      cc0 = p.x; vv0 = __int_as_float(p.y);
      const float x = f1r + f2in[cc0];
      e0 = (x > 0.f) ? x : LEAKY*x;
    }
    if (32 + lane < deg) {
      const int2 p = ldnt(&cvp[start + 32 + lane]);
      cc1 = p.x; vv1 = __int_as_float(p.y);
      const float x = f1r + f2in[cc1];
      e1 = (x > 0.f) ? x : LEAKY*x;
    }
    float m = fmaxf(e0, e1);
    #pragma unroll
    for (int msk=1; msk<32; msk<<=1) m = fmaxf(m, __shfl_xor(m, msk));
    const float ex0 = (lane < deg) ? __expf(e0 - m) : 0.f;
    const float ex1 = (32 + lane < deg) ? __expf(e1 - m) : 0.f;
    float s = ex0 + ex1;
    #pragma unroll
    for (int msk=1; msk<32; msk<<=1) s += __shfl_xor(s, msk);
    const float lgs = LG / s;
    const int npass = (deg + 3) >> 2;
    if (lane < deg)
      rowbuf[hw][lane] = make_int2(cc0, __float_as_int((1.f-LG)*vv0 + ex0*lgs));
    if (32 + lane < deg)
      rowbuf[hw][32 + lane] = make_int2(cc1, __float_as_int((1.f-LG)*vv1 + ex1*lgs));
    for (int z = deg + lane; z < 4*npass; z += 32) rowbuf[hw][z] = make_int2(0, 0);
    asm volatile("s_waitcnt lgkmcnt(0)" ::: "memory");
    for (int p0 = 0; p0 < npass; p0 += 8) {
      int4 pr[8]; ushort_t u0[8], u1[8];
      #pragma unroll
      for (int j=0;j<8;++j) {
        if (p0 + j < npass)
          pr[j] = *(const int4*)(&rowbuf[hw][(p0+j)*4 + g*2]);
        else
          pr[j] = make_int4(0, 0, 0, 0);
      }
      #pragma unroll
      for (int j=0;j<8;++j) {
        u0[j] = Z1b[(size_t)pr[j].x*NC + c];
        u1[j] = Z1b[(size_t)pr[j].z*NC + c];
      }
      #pragma unroll
      for (int j=0;j<8;++j) {
        accv += __int_as_float(pr[j].y) * bf16f(u0[j]);
        accv += __int_as_float(pr[j].w) * bf16f(u1[j]);
      }
    }
    accv += __shfl_xor(accv, 16);
  }
  if (g == 0) {
    const float z0v = Z0[(size_t)row*NC + c];
    const float z1v = bf16f(Z1b[(size_t)row*NC + c]);
    const float wv  = Wat[(size_t)row*NC + c];
    float t0 = z0v*wv, t1 = z1v*wv, t2 = accv*wv;
    #pragma unroll
    for (int msk=1; msk<16; msk<<=1) {
      t0 += __shfl_xor(t0, msk); t1 += __shfl_xor(t1, msk); t2 += __shfl_xor(t2, msk);
    }
    const float mm = fmaxf(t0, fmaxf(t1, t2));
    const float q0 = __expf(t0-mm), q1 = __expf(t1-mm), q2 = __expf(t2-mm);
    const float inv = 1.f/(q0+q1+q2);
    outp[(size_t)row*NC + c] = (q0*z0v + q1*z1v + q2*accv)*inv;
  }
}

extern "C" void kernel_launch(void* const* d_in, const int* in_sizes, int n_in,
                              void* d_out, int out_size, void* d_ws, size_t ws_size,
                              hipStream_t stream) {
  const float* X   = (const float*)d_in[0];
  const float* W0  = (const float*)d_in[1];
  const float* W1  = (const float*)d_in[2];
  const float* a1  = (const float*)d_in[3];
  const float* a2  = (const float*)d_in[4];
  const float* Wat = (const float*)d_in[5];
  const float* gcn = (const float*)d_in[6];
  const int*   ei  = (const int*)d_in[7];
  const int* src = ei;
  const int* dst = ei + NE;
  float* out = (float*)d_out;

  // workspace layout (element offsets; 16B alignment maintained)
  float* Z0      = (float*)d_ws;             // NN*NC f32 (for final mix)
  ushort_t* Z0b  = (ushort_t*)(Z0 + (size_t)NN*NC);  // NN*NC bf16 (hop1 gather table)
  ushort_t* Z1b  = Z0b + (size_t)NN*NC;      // NN*NC bf16 (hop2 gather table)
  float* fA1  = (float*)(Z1b + (size_t)NN*NC); // NN
  float* fA2  = fA1 + NN;                    // NN
  float* fB1  = fA2 + NN;                    // NN
  float* fB2  = fB1 + NN;                    // NN
  int* rowptr = (int*)(fB2 + NN);            // NN+4
  int* bcnt   = rowptr + (NN + 4);           // 256
  int* gcur   = bcnt + 256;                  // 256
  short* W0T  = (short*)(gcur + 256);        // 64*512 shorts (bf16 RNE)
  int2* cvp   = (int2*)(W0T + HIDN*FIN);     // NE int2 packed (col,val)
  int2* tmp   = cvp + NE;                    // NBUCK*SLACK int2 (dead after k_binB)

  k_w0t<<<(HIDN*FIN + 255)/256, 256, 0, stream>>>(W0, W0T, bcnt, gcur);
  k_mlp3<<<MLP_BLKS, 256, 0, stream>>>(X, W0T, W1, a1, a2, Z0, Z0b, fA1, fA2);
  k_binA<<<(NE + TILE_A - 1)/TILE_A, 512, 0, stream>>>(src, dst, gcn, bcnt, gcur, tmp);
  k_binB<<<NBUCK, 512, 0, stream>>>(bcnt, tmp, rowptr, cvp);
  k_hop<<<12500, 256, 0, stream>>>(rowptr, cvp, Z0b, fA1, fA2, Z1b, fB1, fB2, a1, a2);
  k_hop2mix<<<12500, 256, 0, stream>>>(rowptr, cvp, Z1b, fB1, fB2, Z0, Wat, out);
}

// Round 16
// 227.163 us; speedup vs baseline: 1.3982x; 1.0372x over previous
//
#include <hip/hip_runtime.h>
#include <hip/hip_fp16.h>

#define NN 100000
#define NE 3200000
#define FIN 512
#define HIDN 64
#define NC 16
#define LEAKY 0.2f
#define LG 0.2f

// MFMA MLP params
#define GM 256        // rows per block (8 waves x 32 rows)
#define HLD2 72       // H row stride in LDS (bf16 shorts, 144B = 16B-aligned)
#define MLP_BLKS 391  // ceil(100000/256)

// bucket sort params
#define BSH 9                 // 512 nodes per bucket
#define NBUCK 196             // ceil(100000/512)
#define TILE_A 4096           // edges per binA block (512 threads x 8)
#define SLACK 20480           // slack-allocated tmp region per bucket (mean 16327)

typedef float4 f4;
typedef short bf16x8 __attribute__((ext_vector_type(8)));
typedef float f32x4 __attribute__((ext_vector_type(4)));
typedef unsigned short ushort_t;

__device__ __forceinline__ bf16x8 cvt8(const f4 a, const f4 b) {
  union { unsigned u[4]; bf16x8 v; } o;
  asm("v_cvt_pk_bf16_f32 %0, %1, %2" : "=v"(o.u[0]) : "v"(a.x), "v"(a.y));
  asm("v_cvt_pk_bf16_f32 %0, %1, %2" : "=v"(o.u[1]) : "v"(a.z), "v"(a.w));
  asm("v_cvt_pk_bf16_f32 %0, %1, %2" : "=v"(o.u[2]) : "v"(b.x), "v"(b.y));
  asm("v_cvt_pk_bf16_f32 %0, %1, %2" : "=v"(o.u[3]) : "v"(b.z), "v"(b.w));
  return o.v;
}

__device__ __forceinline__ float bf16f(ushort_t s) {
  return __uint_as_float(((unsigned)s) << 16);
}
__device__ __forceinline__ ushort_t f2bf(float f) {
  const unsigned u = __float_as_uint(f);
  return (ushort_t)((u + 0x7fffu + ((u >> 16) & 1u)) >> 16);   // RNE
}
// non-temporal 8B load of an (int,int) pair
__device__ __forceinline__ int2 ldnt(const int2* p) {
  const int* q = (const int*)p;
  int2 r;
  r.x = __builtin_nontemporal_load(q);
  r.y = __builtin_nontemporal_load(q + 1);
  return r;
}

// ---------------- prep: W0 -> W0^T bf16; zeroes bcnt, inits slack cursors ----------------
__global__ __launch_bounds__(256) void k_w0t(const float* __restrict__ W0,
                                             short* __restrict__ W0T,
                                             int* __restrict__ bcnt,
                                             int* __restrict__ gcur) {
  const int i = blockIdx.x*256 + threadIdx.x;   // i = c*512 + k
  if (blockIdx.x == 0) {
    bcnt[threadIdx.x] = 0;                      // k_binA runs after us in-stream
    gcur[threadIdx.x] = threadIdx.x * SLACK;    // slack-region cursors
  }
  if (i >= HIDN*FIN) return;
  const int c = i >> 9, k = i & 511;
  W0T[i] = (short)f2bf(W0[(size_t)k*HIDN + c]);
}

// ---------------- MLP: Z = relu(X@W0)@W1 ; 512 thr / 256 rows: 16 waves/CU ----------------
__global__ __launch_bounds__(512, 2) void k_mlp3(
    const float* __restrict__ X, const short* __restrict__ W0T,
    const float* __restrict__ W1, const float* __restrict__ a1v,
    const float* __restrict__ a2v, float* __restrict__ Z,
    ushort_t* __restrict__ Zb, float* __restrict__ f1o, float* __restrict__ f2o)
{
  __shared__ __align__(16) char smem[HIDN*FIN*2];       // 64 KB total
  short* Wb = (short*)smem;                             // XOR-swizzled bf16 W^T (k-loop)
  short (*HsB)[HLD2] = (short(*)[HLD2])smem;            // aliased after k-loop (36.9 KB)
  float* W1s = (float*)(smem + GM*HLD2*2);              // 4 KB, after HsB region
  const int t = threadIdx.x;
  const int wid = t >> 6, lane = t & 63;                // wid 0..7
  const int r = lane & 15, g = lane >> 4;
  const int rowbase = blockIdx.x*GM + wid*32;
  int row0 = rowbase + r;       if (row0 >= NN) row0 = NN-1;
  int row1 = rowbase + 16 + r;  if (row1 >= NN) row1 = NN-1;
  const float* pa0 = X + (size_t)row0*FIN + g*8;
  const float* pa1 = X + (size_t)row1*FIN + g*8;

  f4 xs[4][2][2];
  #pragma unroll
  for (int d=0; d<4; ++d) {
    xs[d][0][0] = *(const f4*)(pa0 + d*32);  xs[d][0][1] = *(const f4*)(pa0 + d*32 + 4);
    xs[d][1][0] = *(const f4*)(pa1 + d*32);  xs[d][1][1] = *(const f4*)(pa1 + d*32 + 4);
  }

  #pragma unroll
  for (int i2 = 0; i2 < 8; ++i2) {
    const int i = t + i2*512;          // 0..4095 chunks of 16B
    const int row = i >> 6;
    const int cb = (i & 63) << 4;
    const bf16x8 v = *(const bf16x8*)(W0T + (size_t)row*FIN + (i & 63)*8);
    *(bf16x8*)((char*)Wb + row*1024 + (cb ^ ((row & 7) << 4))) = v;
  }
  __syncthreads();

  f32x4 acc[2][4];
  #pragma unroll
  for (int m=0;m<2;++m)
    #pragma unroll
    for (int n=0;n<4;++n) acc[m][n] = (f32x4){0.f,0.f,0.f,0.f};

  #pragma unroll
  for (int ks=0; ks<16; ++ks) {
    const int st = ks & 3;
    bf16x8 bh[4];
    #pragma unroll
    for (int n=0;n<4;++n) {
      const int wrow = n*16 + r;
      const int boff = wrow*1024 + ((ks*64 + g*16) ^ ((wrow & 7) << 4));
      bh[n] = *(const bf16x8*)((const char*)Wb + boff);
    }
    const bf16x8 xb0 = cvt8(xs[st][0][0], xs[st][0][1]);
    const bf16x8 xb1 = cvt8(xs[st][1][0], xs[st][1][1]);
    if (ks + 4 < 16) {
      const int ko = (ks+4)*32;
      xs[st][0][0] = *(const f4*)(pa0 + ko);  xs[st][0][1] = *(const f4*)(pa0 + ko + 4);
      xs[st][1][0] = *(const f4*)(pa1 + ko);  xs[st][1][1] = *(const f4*)(pa1 + ko + 4);
    }
    #pragma unroll
    for (int n=0;n<4;++n) {
      acc[0][n] = __builtin_amdgcn_mfma_f32_16x16x32_bf16(xb0, bh[n], acc[0][n], 0,0,0);
      acc[1][n] = __builtin_amdgcn_mfma_f32_16x16x32_bf16(xb1, bh[n], acc[1][n], 0,0,0);
    }
  }
  __syncthreads();   // all waves done reading Wb before overwrite with H

  #pragma unroll
  for (int m=0;m<2;++m) {
    const int hr = wid*32 + m*16 + g*4;
    #pragma unroll
    for (int n=0;n<4;++n)
      #pragma unroll
      for (int q=0;q<4;++q)
        HsB[hr+q][n*16+r] = (short)f2bf(fmaxf(acc[m][n][q], 0.f));
  }
  if (t < 256) *(f4*)(W1s + t*4) = *(const f4*)(W1 + t*4);
  __syncthreads();

  // layer 2: 2 threads per node (512 thr = 256 nodes); thread handles 8 channels
  {
    const int en = t >> 1, half = t & 1;
    const int node = blockIdx.x*GM + en;
    if (node < NN) {
      float z[8];
      #pragma unroll
      for (int j=0;j<8;++j) z[j]=0.f;
      const bf16x8* hp = (const bf16x8*)(&HsB[en][0]);
      #pragma unroll
      for (int h8=0; h8<8; ++h8) {
        const bf16x8 hv8 = hp[h8];
        #pragma unroll
        for (int j=0;j<8;++j) {
          const float hv = bf16f((ushort_t)hv8[j]);
          const int h = h8*8 + j;
          const f4 wa = *(const f4*)(W1s + h*NC + half*8);
          const f4 wb = *(const f4*)(W1s + h*NC + half*8 + 4);
          z[0]+=hv*wa.x; z[1]+=hv*wa.y; z[2]+=hv*wa.z; z[3]+=hv*wa.w;
          z[4]+=hv*wb.x; z[5]+=hv*wb.y; z[6]+=hv*wb.z; z[7]+=hv*wb.w;
        }
      }
      f4* zp = (f4*)(Z + (size_t)node*NC + half*8);
      zp[0] = make_float4(z[0],z[1],z[2],z[3]);
      zp[1] = make_float4(z[4],z[5],z[6],z[7]);
      bf16x8 zb;
      #pragma unroll
      for (int j=0;j<8;++j) zb[j] = (short)f2bf(z[j]);
      *(bf16x8*)(Zb + (size_t)node*NC + half*8) = zb;
      float s1=0.f, s2=0.f;
      #pragma unroll
      for (int j=0;j<8;++j) { s1 += z[j]*a1v[half*8+j]; s2 += z[j]*a2v[half*8+j]; }
      s1 += __shfl_xor(s1, 1);
      s2 += __shfl_xor(s2, 1);
      if (half == 0) { f1o[node] = s1; f2o[node] = s2; }
    }
  }
}

// ---------------- CSR build phase A: fused histogram + multi-split (slack regions) ----------------
__global__ __launch_bounds__(512) void k_binA(const int* __restrict__ src,
    const int* __restrict__ dst, const float* __restrict__ gcn,
    int* __restrict__ bcnt, int* __restrict__ gcur, int2* __restrict__ tmp)
{
  __shared__ int cnt[256];
  __shared__ int scn[256];
  __shared__ int cur[256];
  __shared__ int gbase[256];
  __shared__ int2 stage[TILE_A];
  __shared__ unsigned char sb[TILE_A];
  const int t = threadIdx.x;
  const int e0 = blockIdx.x*TILE_A;
  const int ecount = min(TILE_A, NE - e0);
  if (t < 256) cnt[t] = 0;
  __syncthreads();
  int w0v[8], w1v[8], bv[8];
  #pragma unroll
  for (int it=0; it<8; ++it) {
    const int i = e0 + it*512 + t;
    bv[it] = -1;
    if (i < NE) {
      const int s_ = src[i];
      const int b = s_ >> BSH;
      bv[it] = b;
      w0v[it] = dst[i] | ((s_ & ((1<<BSH)-1)) << 17);
      w1v[it] = __float_as_int(gcn[i]);
      atomicAdd(&cnt[b], 1);
    }
  }
  __syncthreads();
  if (t < 256) scn[t] = cnt[t];
  __syncthreads();
  for (int off=1; off<256; off<<=1) {
    const int x = (t>=off && t<256) ? scn[t-off] : 0;
    __syncthreads();
    if (t < 256) scn[t] += x;
    __syncthreads();
  }
  if (t < 256) {
    cur[t] = scn[t] - cnt[t];
    if (cnt[t] > 0) {
      gbase[t] = atomicAdd(&gcur[t], cnt[t]);   // slack-region cursor (init t*SLACK)
      atomicAdd(&bcnt[t], cnt[t]);              // global per-bucket count
    }
  }
  __syncthreads();
  #pragma unroll
  for (int it=0; it<8; ++it) {
    if (bv[it] >= 0) {
      const int pos = atomicAdd(&cur[bv[it]], 1);
      stage[pos] = make_int2(w0v[it], w1v[it]);
      sb[pos] = (unsigned char)bv[it];
    }
  }
  __syncthreads();
  #pragma unroll
  for (int it=0; it<8; ++it) {
    const int slot = it*512 + t;
    if (slot < ecount) {
      const int b = sb[slot];
      const int gd = gbase[b] + slot - (scn[b] - cnt[b]);
      tmp[gd] = stage[slot];
    }
  }
}

// ---------------- CSR build phase B: self-based fine sort -> packed (col,val) ----------------
__global__ __launch_bounds__(512) void k_binB(const int* __restrict__ bcnt,
    const int2* __restrict__ tmp, int* __restrict__ rowptr, int2* __restrict__ cvp)
{
  __shared__ int cnt[512];
  __shared__ int scn[512];
  __shared__ int cur[512];
  __shared__ int bs[256];
  __shared__ int baseSh;
  const int t = threadIdx.x;
  const int b = blockIdx.x;
  const int node0 = b << BSH;
  const int n = bcnt[b];
  const int2* tsl = tmp + (size_t)b*SLACK;
  // compute true CSR base: exclusive prefix of bcnt over buckets
  if (t < 256) bs[t] = (t < NBUCK) ? bcnt[t] : 0;
  cnt[t] = 0;
  __syncthreads();
  for (int off=1; off<256; off<<=1) {
    const int x = (t>=off && t<256) ? bs[t-off] : 0;
    __syncthreads();
    if (t < 256) bs[t] += x;
    __syncthreads();
  }
  if (t == 0) baseSh = bs[b] - n;
  __syncthreads();
  const int base = baseSh;
  // per-src histogram of this bucket
  for (int i = t; i < n; i += 512)
    atomicAdd(&cnt[tsl[i].x >> 17], 1);
  __syncthreads();
  scn[t] = cnt[t];
  __syncthreads();
  for (int off=1; off<512; off<<=1) {
    const int x = (t>=off) ? scn[t-off] : 0;
    __syncthreads();
    scn[t] += x;
    __syncthreads();
  }
  const int excl = scn[t] - cnt[t];
  cur[t] = excl;
  if (node0 + t < NN) rowptr[node0 + t] = base + excl;
  if (b == 0 && t == 0) rowptr[NN] = NE;
  __syncthreads();
  for (int i = t; i < n; i += 512) {
    const int2 e = tsl[i];
    const int ls = e.x >> 17;
    const int p = base + atomicAdd(&cur[ls], 1);
    cvp[p] = make_int2(e.x & 0x1FFFF, e.y);
  }
}

// ---------------- hop 1: bf16 L2 gathers, batched-issue PV pipeline ----------------
__global__ __launch_bounds__(256) void k_hop(const int* __restrict__ rowptr,
    const int2* __restrict__ cvp,
    const ushort_t* __restrict__ Zb, const float* __restrict__ f1in,
    const float* __restrict__ f2in, ushort_t* __restrict__ Zoutb,
    float* __restrict__ f1out, float* __restrict__ f2out,
    const float* __restrict__ a1v, const float* __restrict__ a2v)
{
  __shared__ __align__(16) int2 rowbuf[8][64];
  const int t = threadIdx.x;
  const int lane = t & 31;
  const int hw = t >> 5;
  const int row = blockIdx.x*8 + hw;
  if (row >= NN) return;
  const int start = rowptr[row], end = rowptr[row+1];
  const int deg = end - start;
  const int c = lane & 15, g = (lane >> 4) & 1;

  if (deg == 0) {
    if (g == 0) {
      Zoutb[(size_t)row*NC + c] = 0;
      if (c == 0) { f1out[row] = 0.f; f2out[row] = 0.f; }
    }
    return;
  }
  const float f1r = f1in[row];

  if (deg <= 64) {
    int cc0 = 0, cc1 = 0; float vv0 = 0.f, vv1 = 0.f;
    float e0 = -1e30f, e1 = -1e30f;
    if (lane < deg) {
      const int2 p = ldnt(&cvp[start + lane]);
      cc0 = p.x; vv0 = __int_as_float(p.y);
      const float x = f1r + f2in[cc0];
      e0 = (x > 0.f) ? x : LEAKY*x;
    }
    if (32 + lane < deg) {
      const int2 p = ldnt(&cvp[start + 32 + lane]);
      cc1 = p.x; vv1 = __int_as_float(p.y);
      const float x = f1r + f2in[cc1];
      e1 = (x > 0.f) ? x : LEAKY*x;
    }
    float m = fmaxf(e0, e1);
    #pragma unroll
    for (int msk=1; msk<32; msk<<=1) m = fmaxf(m, __shfl_xor(m, msk));
    const float ex0 = (lane < deg) ? __expf(e0 - m) : 0.f;
    const float ex1 = (32 + lane < deg) ? __expf(e1 - m) : 0.f;
    float s = ex0 + ex1;
    #pragma unroll
    for (int msk=1; msk<32; msk<<=1) s += __shfl_xor(s, msk);
    const float lgs = LG / s;
    const int npass = (deg + 3) >> 2;
    if (lane < deg)
      rowbuf[hw][lane] = make_int2(cc0, __float_as_int((1.f-LG)*vv0 + ex0*lgs));
    if (32 + lane < deg)
      rowbuf[hw][32 + lane] = make_int2(cc1, __float_as_int((1.f-LG)*vv1 + ex1*lgs));
    for (int z = deg + lane; z < 4*npass; z += 32) rowbuf[hw][z] = make_int2(0, 0);
    asm volatile("s_waitcnt lgkmcnt(0)" ::: "memory");
    float accv = 0.f;
    for (int p0 = 0; p0 < npass; p0 += 8) {
      int4 pr[8]; ushort_t u0[8], u1[8];
      #pragma unroll
      for (int j=0;j<8;++j) {
        if (p0 + j < npass)
          pr[j] = *(const int4*)(&rowbuf[hw][(p0+j)*4 + g*2]);
        else
          pr[j] = make_int4(0, 0, 0, 0);
      }
      #pragma unroll
      for (int j=0;j<8;++j) {
        u0[j] = Zb[(size_t)pr[j].x*NC + c];
        u1[j] = Zb[(size_t)pr[j].z*NC + c];
      }
      #pragma unroll
      for (int j=0;j<8;++j) {
        accv += __int_as_float(pr[j].y) * bf16f(u0[j]);
        accv += __int_as_float(pr[j].w) * bf16f(u1[j]);
      }
    }
    accv += __shfl_xor(accv, 16);
    if (g == 0) {
      Zoutb[(size_t)row*NC + c] = f2bf(accv);
      float s1 = accv * a1v[c];
      float s2 = accv * a2v[c];
      #pragma unroll
      for (int msk=1; msk<16; msk<<=1) { s1 += __shfl_xor(s1, msk); s2 += __shfl_xor(s2, msk); }
      if (c == 0) { f1out[row] = s1; f2out[row] = s2; }
    }
  } else {
    const int nit = (deg + 31) >> 5;
    float m = -1e30f;
    for (int it=0; it<nit; ++it) {
      const int idx = start + it*32 + lane;
      if (idx < end) {
        const int2 p = ldnt(&cvp[idx]);
        const float x = f1r + f2in[p.x];
        m = fmaxf(m, (x>0.f)?x:LEAKY*x);
      }
    }
    #pragma unroll
    for (int msk=1; msk<32; msk<<=1) m = fmaxf(m, __shfl_xor(m, msk));
    float s = 0.f;
    for (int it=0; it<nit; ++it) {
      const int idx = start + it*32 + lane;
      if (idx < end) {
        const int2 p = ldnt(&cvp[idx]);
        const float x = f1r + f2in[p.x];
        s += __expf(((x>0.f)?x:LEAKY*x) - m);
      }
    }
    #pragma unroll
    for (int msk=1; msk<32; msk<<=1) s += __shfl_xor(s, msk);
    const float lgs = LG / s;
    float a[16];
    #pragma unroll
    for (int k=0;k<16;++k) a[k]=0.f;
    for (int it=0; it<nit; ++it) {
      const int idx = start + it*32 + lane;
      if (idx < end) {
        const int2 p = ldnt(&cvp[idx]);
        const float x = f1r + f2in[p.x];
        const float coef = (1.f-LG)*__int_as_float(p.y) + __expf(((x>0.f)?x:LEAKY*x) - m)*lgs;
        const ushort_t* zp = Zb + (size_t)p.x*NC;
        #pragma unroll
        for (int k=0;k<16;++k) a[k] += coef * bf16f(zp[k]);
      }
    }
    #pragma unroll
    for (int msk=1; msk<32; msk<<=1) {
      #pragma unroll
      for (int k=0;k<16;++k) a[k] += __shfl_xor(a[k], msk);
    }
    if (lane == 0) {
      #pragma unroll
      for (int k=0;k<16;++k) Zoutb[(size_t)row*NC + k] = f2bf(a[k]);
      float s1=0.f, s2=0.f;
      #pragma unroll
      for (int k=0;k<16;++k) { s1 += a[k]*a1v[k]; s2 += a[k]*a2v[k]; }
      f1out[row]=s1; f2out[row]=s2;
    }
  }
}

// ---------------- hop 2 fused with the per-node 3-hop attention mix ----------------
__global__ __launch_bounds__(256) void k_hop2mix(const int* __restrict__ rowptr,
    const int2* __restrict__ cvp,
    const ushort_t* __restrict__ Z1b, const float* __restrict__ f1in,
    const float* __restrict__ f2in, const float* __restrict__ Z0,
    const float* __restrict__ Wat, float* __restrict__ outp)
{
  __shared__ __align__(16) int2 rowbuf[8][64];
  const int t = threadIdx.x;
  const int lane = t & 31;
  const int hw = t >> 5;
  const int row = blockIdx.x*8 + hw;
  if (row >= NN) return;
  const int start = rowptr[row], end = rowptr[row+1];
  const int deg = end - start;
  const int c = lane & 15, g = (lane >> 4) & 1;

  if (deg > 64) {
    const float f1r = f1in[row];
    const int nit = (deg + 31) >> 5;
    float m = -1e30f;
    for (int it=0; it<nit; ++it) {
      const int idx = start + it*32 + lane;
      if (idx < end) {
        const float x = f1r + f2in[ldnt(&cvp[idx]).x];
        m = fmaxf(m, (x>0.f)?x:LEAKY*x);
      }
    }
    #pragma unroll
    for (int msk=1; msk<32; msk<<=1) m = fmaxf(m, __shfl_xor(m, msk));
    float s = 0.f;
    for (int it=0; it<nit; ++it) {
      const int idx = start + it*32 + lane;
      if (idx < end) {
        const float x = f1r + f2in[ldnt(&cvp[idx]).x];
        s += __expf(((x>0.f)?x:LEAKY*x) - m);
      }
    }
    #pragma unroll
    for (int msk=1; msk<32; msk<<=1) s += __shfl_xor(s, msk);
    const float lgs = LG / s;
    float a[16];
    #pragma unroll
    for (int k=0;k<16;++k) a[k]=0.f;
    for (int it=0; it<nit; ++it) {
      const int idx = start + it*32 + lane;
      if (idx < end) {
        const int2 p = ldnt(&cvp[idx]);
        const float x = f1r + f2in[p.x];
        const float coef = (1.f-LG)*__int_as_float(p.y) + __expf(((x>0.f)?x:LEAKY*x) - m)*lgs;
        const ushort_t* zp = Z1b + (size_t)p.x*NC;
        #pragma unroll
        for (int k=0;k<16;++k) a[k] += coef * bf16f(zp[k]);
      }
    }
    #pragma unroll
    for (int msk=1; msk<32; msk<<=1) {
      #pragma unroll
      for (int k=0;k<16;++k) a[k] += __shfl_xor(a[k], msk);
    }
    if (lane == 0) {
      float t0=0.f, t1=0.f, t2=0.f;
      for (int k=0;k<16;++k) {
        const float w = Wat[(size_t)row*NC + k];
        t0 += Z0[(size_t)row*NC + k]*w;
        t1 += bf16f(Z1b[(size_t)row*NC + k])*w;
        t2 += a[k]*w;
      }
      const float mm = fmaxf(t0, fmaxf(t1, t2));
      const float q0 = __expf(t0-mm), q1 = __expf(t1-mm), q2 = __expf(t2-mm);
      const float inv = 1.f/(q0+q1+q2);
      for (int k=0;k<16;++k)
        outp[(size_t)row*NC + k] =
          (q0*Z0[(size_t)row*NC + k] + q1*bf16f(Z1b[(size_t)row*NC + k]) + q2*a[k])*inv;
    }
    return;
  }

  float accv = 0.f;
  if (deg > 0) {
    const float f1r = f1in[row];
    int cc0 = 0, cc1 = 0; float vv0 = 0.f, vv1 = 0.f;
    float e0 = -1e30f, e1 = -1e30f;
    if (lane < deg) {
      const int2 p = ldnt(&cvp[start + lane]);
      cc0 = p.x; vv0 = __int_as_float(p.y);
      const float x = f1r + f2in[cc0];
      e0 = (x > 0.f) ? x : LEAKY*x;
    }
    if (32 + lane < deg) {
      const int2 p = ldnt(&cvp[start + 32 + lane]);
      cc1 = p.x; vv1 = __int_as_float(p.y);
      const float x = f1r + f2in[cc1];
      e1 = (x > 0.f) ? x : LEAKY*x;
    }
    float m = fmaxf(e0, e1);
    #pragma unroll
    for (int msk=1; msk<32; msk<<=1) m = fmaxf(m, __shfl_xor(m, msk));
    const float ex0 = (lane < deg) ? __expf(e0 - m) : 0.f;
    const float ex1 = (32 + lane < deg) ? __expf(e1 - m) : 0.f;
    float s = ex0 + ex1;
    #pragma unroll
    for (int msk=1; msk<32; msk<<=1) s += __shfl_xor(s, msk);
    const float lgs = LG / s;
    const int npass = (deg + 3) >> 2;
    if (lane < deg)
      rowbuf[hw][lane] = make_int2(cc0, __float_as_int((1.f-LG)*vv0 + ex0*lgs));
    if (32 + lane < deg)
      rowbuf[hw][32 + lane] = make_int2(cc1, __float_as_int((1.f-LG)*vv1 + ex1*lgs));
    for (int z = deg + lane; z < 4*npass; z += 32) rowbuf[hw][z] = make_int2(0, 0);
    asm volatile("s_waitcnt lgkmcnt(0)" ::: "memory");
    for (int p0 = 0; p0 < npass; p0 += 8) {
      int4 pr[8]; ushort_t u0[8], u1[8];
      #pragma unroll
      for (int j=0;j<8;++j) {
        if (p0 + j < npass)
          pr[j] = *(const int4*)(&rowbuf[hw][(p0+j)*4 + g*2]);
        else
          pr[j] = make_int4(0, 0, 0, 0);
      }
      #pragma unroll
      for (int j=0;j<8;++j) {
        u0[j] = Z1b[(size_t)pr[j].x*NC + c];
        u1[j] = Z1b[(size_t)pr[j].z*NC + c];
      }
      #pragma unroll
      for (int j=0;j<8;++j) {
        accv += __int_as_float(pr[j].y) * bf16f(u0[j]);
        accv += __int_as_float(pr[j].w) * bf16f(u1[j]);
      }
    }
    accv += __shfl_xor(accv, 16);
  }
  if (g == 0) {
    const float z0v = Z0[(size_t)row*NC + c];
    const float z1v = bf16f(Z1b[(size_t)row*NC + c]);
    const float wv  = Wat[(size_t)row*NC + c];
    float t0 = z0v*wv, t1 = z1v*wv, t2 = accv*wv;
    #pragma unroll
    for (int msk=1; msk<16; msk<<=1) {
      t0 += __shfl_xor(t0, msk); t1 += __shfl_xor(t1, msk); t2 += __shfl_xor(t2, msk);
    }
    const float mm = fmaxf(t0, fmaxf(t1, t2));
    const float q0 = __expf(t0-mm), q1 = __expf(t1-mm), q2 = __expf(t2-mm);
    const float inv = 1.f/(q0+q1+q2);
    outp[(size_t)row*NC + c] = (q0*z0v + q1*z1v + q2*accv)*inv;
  }
}

extern "C" void kernel_launch(void* const* d_in, const int* in_sizes, int n_in,
                              void* d_out, int out_size, void* d_ws, size_t ws_size,
                              hipStream_t stream) {
  const float* X   = (const float*)d_in[0];
  const float* W0  = (const float*)d_in[1];
  const float* W1  = (const float*)d_in[2];
  const float* a1  = (const float*)d_in[3];
  const float* a2  = (const float*)d_in[4];
  const float* Wat = (const float*)d_in[5];
  const float* gcn = (const float*)d_in[6];
  const int*   ei  = (const int*)d_in[7];
  const int* src = ei;
  const int* dst = ei + NE;
  float* out = (float*)d_out;

  // workspace layout (element offsets; 16B alignment maintained)
  float* Z0      = (float*)d_ws;             // NN*NC f32 (for final mix)
  ushort_t* Z0b  = (ushort_t*)(Z0 + (size_t)NN*NC);  // NN*NC bf16 (hop1 gather table)
  ushort_t* Z1b  = Z0b + (size_t)NN*NC;      // NN*NC bf16 (hop2 gather table)
  float* fA1  = (float*)(Z1b + (size_t)NN*NC); // NN
  float* fA2  = fA1 + NN;                    // NN
  float* fB1  = fA2 + NN;                    // NN
  float* fB2  = fB1 + NN;                    // NN
  int* rowptr = (int*)(fB2 + NN);            // NN+4
  int* bcnt   = rowptr + (NN + 4);           // 256
  int* gcur   = bcnt + 256;                  // 256
  short* W0T  = (short*)(gcur + 256);        // 64*512 shorts (bf16 RNE)
  int2* cvp   = (int2*)(W0T + HIDN*FIN);     // NE int2 packed (col,val)
  int2* tmp   = cvp + NE;                    // NBUCK*SLACK int2 (dead after k_binB)

  k_w0t<<<(HIDN*FIN + 255)/256, 256, 0, stream>>>(W0, W0T, bcnt, gcur);
  k_mlp3<<<MLP_BLKS, 512, 0, stream>>>(X, W0T, W1, a1, a2, Z0, Z0b, fA1, fA2);
  k_binA<<<(NE + TILE_A - 1)/TILE_A, 512, 0, stream>>>(src, dst, gcn, bcnt, gcur, tmp);
  k_binB<<<NBUCK, 512, 0, stream>>>(bcnt, tmp, rowptr, cvp);
  k_hop<<<12500, 256, 0, stream>>>(rowptr, cvp, Z0b, fA1, fA2, Z1b, fB1, fB2, a1, a2);
  k_hop2mix<<<12500, 256, 0, stream>>>(rowptr, cvp, Z1b, fB1, fB2, Z0, Wat, out);
}

// Round 17
// 204.350 us; speedup vs baseline: 1.5542x; 1.1116x over previous
//
#include <hip/hip_runtime.h>
#include <hip/hip_fp16.h>

#define NN 100000
#define NE 3200000
#define FIN 512
#define HIDN 64
#define NC 16
#define LEAKY 0.2f
#define LG 0.2f

// MFMA MLP params
#define GM 256        // rows per block (8 waves x 32 rows)
#define HLD2 72       // H row stride in LDS (bf16 shorts, 144B = 16B-aligned)
#define MLP_BLKS 391  // ceil(100000/256)

// bucket sort params
#define BSH 9                 // 512 nodes per bucket
#define NBUCK 196             // ceil(100000/512)
#define TILE_A 4096           // edges per binA block (512 threads x 8)
#define NBINA 782             // ceil(NE/TILE_A)
#define SLACK 20480           // slack-allocated tmp region per bucket (mean 16327)

typedef float4 f4;
typedef short bf16x8 __attribute__((ext_vector_type(8)));
typedef float f32x4 __attribute__((ext_vector_type(4)));
typedef unsigned short ushort_t;

__device__ __forceinline__ bf16x8 cvt8(const f4 a, const f4 b) {
  union { unsigned u[4]; bf16x8 v; } o;
  asm("v_cvt_pk_bf16_f32 %0, %1, %2" : "=v"(o.u[0]) : "v"(a.x), "v"(a.y));
  asm("v_cvt_pk_bf16_f32 %0, %1, %2" : "=v"(o.u[1]) : "v"(a.z), "v"(a.w));
  asm("v_cvt_pk_bf16_f32 %0, %1, %2" : "=v"(o.u[2]) : "v"(b.x), "v"(b.y));
  asm("v_cvt_pk_bf16_f32 %0, %1, %2" : "=v"(o.u[3]) : "v"(b.z), "v"(b.w));
  return o.v;
}

__device__ __forceinline__ float bf16f(ushort_t s) {
  return __uint_as_float(((unsigned)s) << 16);
}
__device__ __forceinline__ ushort_t f2bf(float f) {
  const unsigned u = __float_as_uint(f);
  return (ushort_t)((u + 0x7fffu + ((u >> 16) & 1u)) >> 16);   // RNE
}
// non-temporal 8B load of an (int,int) pair
__device__ __forceinline__ int2 ldnt(const int2* p) {
  const int* q = (const int*)p;
  int2 r;
  r.x = __builtin_nontemporal_load(q);
  r.y = __builtin_nontemporal_load(q + 1);
  return r;
}

// ---------------- prep: W0 -> W0^T bf16; zeroes bcnt, inits slack cursors ----------------
__global__ __launch_bounds__(256) void k_w0t(const float* __restrict__ W0,
                                             short* __restrict__ W0T,
                                             int* __restrict__ bcnt,
                                             int* __restrict__ gcur) {
  const int i = blockIdx.x*256 + threadIdx.x;   // i = c*512 + k
  if (blockIdx.x == 0) {
    bcnt[threadIdx.x] = 0;                      // fused kernel runs after us in-stream
    gcur[threadIdx.x] = threadIdx.x * SLACK;    // slack-region cursors
  }
  if (i >= HIDN*FIN) return;
  const int c = i >> 9, k = i & 511;
  W0T[i] = (short)f2bf(W0[(size_t)k*HIDN + c]);
}

// ---------------- fused: blocks [0,MLP_BLKS) = MLP ; [MLP_BLKS, +NBINA) = binA ----------------
// Independent dataflows co-resident on each CU: binA's edge streaming fills the
// MLP's HBM-latency stall slots (stream order would serialize them).
__global__ __launch_bounds__(512, 2) void k_mlpA(
    const float* __restrict__ X, const short* __restrict__ W0T,
    const float* __restrict__ W1, const float* __restrict__ a1v,
    const float* __restrict__ a2v, float* __restrict__ Z,
    ushort_t* __restrict__ Zb, float* __restrict__ f1o, float* __restrict__ f2o,
    const int* __restrict__ src, const int* __restrict__ dst,
    const float* __restrict__ gcn, int* __restrict__ bcnt,
    int* __restrict__ gcur, int2* __restrict__ tmp)
{
  __shared__ __align__(16) char smem[HIDN*FIN*2];       // 64 KB union
  const int t = threadIdx.x;

  if (blockIdx.x < MLP_BLKS) {
    // ================= MLP path (identical body to R16 k_mlp3) =================
    short* Wb = (short*)smem;
    short (*HsB)[HLD2] = (short(*)[HLD2])smem;
    float* W1s = (float*)(smem + GM*HLD2*2);
    const int wid = t >> 6, lane = t & 63;
    const int r = lane & 15, g = lane >> 4;
    const int rowbase = blockIdx.x*GM + wid*32;
    int row0 = rowbase + r;       if (row0 >= NN) row0 = NN-1;
    int row1 = rowbase + 16 + r;  if (row1 >= NN) row1 = NN-1;
    const float* pa0 = X + (size_t)row0*FIN + g*8;
    const float* pa1 = X + (size_t)row1*FIN + g*8;

    f4 xs[4][2][2];
    #pragma unroll
    for (int d=0; d<4; ++d) {
      xs[d][0][0] = *(const f4*)(pa0 + d*32);  xs[d][0][1] = *(const f4*)(pa0 + d*32 + 4);
      xs[d][1][0] = *(const f4*)(pa1 + d*32);  xs[d][1][1] = *(const f4*)(pa1 + d*32 + 4);
    }

    #pragma unroll
    for (int i2 = 0; i2 < 8; ++i2) {
      const int i = t + i2*512;
      const int row = i >> 6;
      const int cb = (i & 63) << 4;
      const bf16x8 v = *(const bf16x8*)(W0T + (size_t)row*FIN + (i & 63)*8);
      *(bf16x8*)((char*)Wb + row*1024 + (cb ^ ((row & 7) << 4))) = v;
    }
    __syncthreads();

    f32x4 acc[2][4];
    #pragma unroll
    for (int m=0;m<2;++m)
      #pragma unroll
      for (int n=0;n<4;++n) acc[m][n] = (f32x4){0.f,0.f,0.f,0.f};

    #pragma unroll
    for (int ks=0; ks<16; ++ks) {
      const int st = ks & 3;
      bf16x8 bh[4];
      #pragma unroll
      for (int n=0;n<4;++n) {
        const int wrow = n*16 + r;
        const int boff = wrow*1024 + ((ks*64 + g*16) ^ ((wrow & 7) << 4));
        bh[n] = *(const bf16x8*)((const char*)Wb + boff);
      }
      const bf16x8 xb0 = cvt8(xs[st][0][0], xs[st][0][1]);
      const bf16x8 xb1 = cvt8(xs[st][1][0], xs[st][1][1]);
      if (ks + 4 < 16) {
        const int ko = (ks+4)*32;
        xs[st][0][0] = *(const f4*)(pa0 + ko);  xs[st][0][1] = *(const f4*)(pa0 + ko + 4);
        xs[st][1][0] = *(const f4*)(pa1 + ko);  xs[st][1][1] = *(const f4*)(pa1 + ko + 4);
      }
      #pragma unroll
      for (int n=0;n<4;++n) {
        acc[0][n] = __builtin_amdgcn_mfma_f32_16x16x32_bf16(xb0, bh[n], acc[0][n], 0,0,0);
        acc[1][n] = __builtin_amdgcn_mfma_f32_16x16x32_bf16(xb1, bh[n], acc[1][n], 0,0,0);
      }
    }
    __syncthreads();

    #pragma unroll
    for (int m=0;m<2;++m) {
      const int hr = wid*32 + m*16 + g*4;
      #pragma unroll
      for (int n=0;n<4;++n)
        #pragma unroll
        for (int q=0;q<4;++q)
          HsB[hr+q][n*16+r] = (short)f2bf(fmaxf(acc[m][n][q], 0.f));
    }
    if (t < 256) *(f4*)(W1s + t*4) = *(const f4*)(W1 + t*4);
    __syncthreads();

    {
      const int en = t >> 1, half = t & 1;
      const int node = blockIdx.x*GM + en;
      if (node < NN) {
        float z[8];
        #pragma unroll
        for (int j=0;j<8;++j) z[j]=0.f;
        const bf16x8* hp = (const bf16x8*)(&HsB[en][0]);
        #pragma unroll
        for (int h8=0; h8<8; ++h8) {
          const bf16x8 hv8 = hp[h8];
          #pragma unroll
          for (int j=0;j<8;++j) {
            const float hv = bf16f((ushort_t)hv8[j]);
            const int h = h8*8 + j;
            const f4 wa = *(const f4*)(W1s + h*NC + half*8);
            const f4 wb = *(const f4*)(W1s + h*NC + half*8 + 4);
            z[0]+=hv*wa.x; z[1]+=hv*wa.y; z[2]+=hv*wa.z; z[3]+=hv*wa.w;
            z[4]+=hv*wb.x; z[5]+=hv*wb.y; z[6]+=hv*wb.z; z[7]+=hv*wb.w;
          }
        }
        f4* zp = (f4*)(Z + (size_t)node*NC + half*8);
        zp[0] = make_float4(z[0],z[1],z[2],z[3]);
        zp[1] = make_float4(z[4],z[5],z[6],z[7]);
        bf16x8 zb;
        #pragma unroll
        for (int j=0;j<8;++j) zb[j] = (short)f2bf(z[j]);
        *(bf16x8*)(Zb + (size_t)node*NC + half*8) = zb;
        float s1=0.f, s2=0.f;
        #pragma unroll
        for (int j=0;j<8;++j) { s1 += z[j]*a1v[half*8+j]; s2 += z[j]*a2v[half*8+j]; }
        s1 += __shfl_xor(s1, 1);
        s2 += __shfl_xor(s2, 1);
        if (half == 0) { f1o[node] = s1; f2o[node] = s2; }
      }
    }
  } else {
    // ================= binA path (identical body to R16 k_binA) =================
    int* cnt  = (int*)smem;                        // 256
    int* scn  = cnt + 256;                         // 256
    int* cur  = scn + 256;                         // 256
    int* gbase= cur + 256;                         // 256
    int2* stage = (int2*)(gbase + 256);            // TILE_A int2 (32 KB)
    unsigned char* sb = (unsigned char*)(stage + TILE_A);  // TILE_A
    const int blk = blockIdx.x - MLP_BLKS;
    const int e0 = blk*TILE_A;
    const int ecount = min(TILE_A, NE - e0);
    if (t < 256) cnt[t] = 0;
    __syncthreads();
    int w0v[8], w1v[8], bv[8];
    #pragma unroll
    for (int it=0; it<8; ++it) {
      const int i = e0 + it*512 + t;
      bv[it] = -1;
      if (i < NE) {
        const int s_ = src[i];
        const int b = s_ >> BSH;
        bv[it] = b;
        w0v[it] = dst[i] | ((s_ & ((1<<BSH)-1)) << 17);
        w1v[it] = __float_as_int(gcn[i]);
        atomicAdd(&cnt[b], 1);
      }
    }
    __syncthreads();
    if (t < 256) scn[t] = cnt[t];
    __syncthreads();
    for (int off=1; off<256; off<<=1) {
      const int x = (t>=off && t<256) ? scn[t-off] : 0;
      __syncthreads();
      if (t < 256) scn[t] += x;
      __syncthreads();
    }
    if (t < 256) {
      cur[t] = scn[t] - cnt[t];
      if (cnt[t] > 0) {
        gbase[t] = atomicAdd(&gcur[t], cnt[t]);
        atomicAdd(&bcnt[t], cnt[t]);
      }
    }
    __syncthreads();
    #pragma unroll
    for (int it=0; it<8; ++it) {
      if (bv[it] >= 0) {
        const int pos = atomicAdd(&cur[bv[it]], 1);
        stage[pos] = make_int2(w0v[it], w1v[it]);
        sb[pos] = (unsigned char)bv[it];
      }
    }
    __syncthreads();
    #pragma unroll
    for (int it=0; it<8; ++it) {
      const int slot = it*512 + t;
      if (slot < ecount) {
        const int b = sb[slot];
        const int gd = gbase[b] + slot - (scn[b] - cnt[b]);
        tmp[gd] = stage[slot];
      }
    }
  }
}

// ---------------- CSR build phase B: self-based fine sort -> packed (col,val) ----------------
__global__ __launch_bounds__(512) void k_binB(const int* __restrict__ bcnt,
    const int2* __restrict__ tmp, int* __restrict__ rowptr, int2* __restrict__ cvp)
{
  __shared__ int cnt[512];
  __shared__ int scn[512];
  __shared__ int cur[512];
  __shared__ int bs[256];
  __shared__ int baseSh;
  const int t = threadIdx.x;
  const int b = blockIdx.x;
  const int node0 = b << BSH;
  const int n = bcnt[b];
  const int2* tsl = tmp + (size_t)b*SLACK;
  // compute true CSR base: exclusive prefix of bcnt over buckets
  if (t < 256) bs[t] = (t < NBUCK) ? bcnt[t] : 0;
  cnt[t] = 0;
  __syncthreads();
  for (int off=1; off<256; off<<=1) {
    const int x = (t>=off && t<256) ? bs[t-off] : 0;
    __syncthreads();
    if (t < 256) bs[t] += x;
    __syncthreads();
  }
  if (t == 0) baseSh = bs[b] - n;
  __syncthreads();
  const int base = baseSh;
  // per-src histogram of this bucket
  for (int i = t; i < n; i += 512)
    atomicAdd(&cnt[tsl[i].x >> 17], 1);
  __syncthreads();
  scn[t] = cnt[t];
  __syncthreads();
  for (int off=1; off<512; off<<=1) {
    const int x = (t>=off) ? scn[t-off] : 0;
    __syncthreads();
    scn[t] += x;
    __syncthreads();
  }
  const int excl = scn[t] - cnt[t];
  cur[t] = excl;
  if (node0 + t < NN) rowptr[node0 + t] = base + excl;
  if (b == 0 && t == 0) rowptr[NN] = NE;
  __syncthreads();
  for (int i = t; i < n; i += 512) {
    const int2 e = tsl[i];
    const int ls = e.x >> 17;
    const int p = base + atomicAdd(&cur[ls], 1);
    cvp[p] = make_int2(e.x & 0x1FFFF, e.y);
  }
}

// ---------------- hop 1: bf16 L2 gathers, batched-issue PV pipeline ----------------
__global__ __launch_bounds__(256) void k_hop(const int* __restrict__ rowptr,
    const int2* __restrict__ cvp,
    const ushort_t* __restrict__ Zb, const float* __restrict__ f1in,
    const float* __restrict__ f2in, ushort_t* __restrict__ Zoutb,
    float* __restrict__ f1out, float* __restrict__ f2out,
    const float* __restrict__ a1v, const float* __restrict__ a2v)
{
  __shared__ __align__(16) int2 rowbuf[8][64];
  const int t = threadIdx.x;
  const int lane = t & 31;
  const int hw = t >> 5;
  const int row = blockIdx.x*8 + hw;
  if (row >= NN) return;
  const int start = rowptr[row], end = rowptr[row+1];
  const int deg = end - start;
  const int c = lane & 15, g = (lane >> 4) & 1;

  if (deg == 0) {
    if (g == 0) {
      Zoutb[(size_t)row*NC + c] = 0;
      if (c == 0) { f1out[row] = 0.f; f2out[row] = 0.f; }
    }
    return;
  }
  const float f1r = f1in[row];

  if (deg <= 64) {
    int cc0 = 0, cc1 = 0; float vv0 = 0.f, vv1 = 0.f;
    float e0 = -1e30f, e1 = -1e30f;
    if (lane < deg) {
      const int2 p = ldnt(&cvp[start + lane]);
      cc0 = p.x; vv0 = __int_as_float(p.y);
      const float x = f1r + f2in[cc0];
      e0 = (x > 0.f) ? x : LEAKY*x;
    }
    if (32 + lane < deg) {
      const int2 p = ldnt(&cvp[start + 32 + lane]);
      cc1 = p.x; vv1 = __int_as_float(p.y);
      const float x = f1r + f2in[cc1];
      e1 = (x > 0.f) ? x : LEAKY*x;
    }
    float m = fmaxf(e0, e1);
    #pragma unroll
    for (int msk=1; msk<32; msk<<=1) m = fmaxf(m, __shfl_xor(m, msk));
    const float ex0 = (lane < deg) ? __expf(e0 - m) : 0.f;
    const float ex1 = (32 + lane < deg) ? __expf(e1 - m) : 0.f;
    float s = ex0 + ex1;
    #pragma unroll
    for (int msk=1; msk<32; msk<<=1) s += __shfl_xor(s, msk);
    const float lgs = LG / s;
    const int npass = (deg + 3) >> 2;
    if (lane < deg)
      rowbuf[hw][lane] = make_int2(cc0, __float_as_int((1.f-LG)*vv0 + ex0*lgs));
    if (32 + lane < deg)
      rowbuf[hw][32 + lane] = make_int2(cc1, __float_as_int((1.f-LG)*vv1 + ex1*lgs));
    for (int z = deg + lane; z < 4*npass; z += 32) rowbuf[hw][z] = make_int2(0, 0);
    asm volatile("s_waitcnt lgkmcnt(0)" ::: "memory");
    float accv = 0.f;
    for (int p0 = 0; p0 < npass; p0 += 8) {
      int4 pr[8]; ushort_t u0[8], u1[8];
      #pragma unroll
      for (int j=0;j<8;++j) {
        if (p0 + j < npass)
          pr[j] = *(const int4*)(&rowbuf[hw][(p0+j)*4 + g*2]);
        else
          pr[j] = make_int4(0, 0, 0, 0);
      }
      #pragma unroll
      for (int j=0;j<8;++j) {
        u0[j] = Zb[(size_t)pr[j].x*NC + c];
        u1[j] = Zb[(size_t)pr[j].z*NC + c];
      }
      #pragma unroll
      for (int j=0;j<8;++j) {
        accv += __int_as_float(pr[j].y) * bf16f(u0[j]);
        accv += __int_as_float(pr[j].w) * bf16f(u1[j]);
      }
    }
    accv += __shfl_xor(accv, 16);
    if (g == 0) {
      Zoutb[(size_t)row*NC + c] = f2bf(accv);
      float s1 = accv * a1v[c];
      float s2 = accv * a2v[c];
      #pragma unroll
      for (int msk=1; msk<16; msk<<=1) { s1 += __shfl_xor(s1, msk); s2 += __shfl_xor(s2, msk); }
      if (c == 0) { f1out[row] = s1; f2out[row] = s2; }
    }
  } else {
    const int nit = (deg + 31) >> 5;
    float m = -1e30f;
    for (int it=0; it<nit; ++it) {
      const int idx = start + it*32 + lane;
      if (idx < end) {
        const int2 p = ldnt(&cvp[idx]);
        const float x = f1r + f2in[p.x];
        m = fmaxf(m, (x>0.f)?x:LEAKY*x);
      }
    }
    #pragma unroll
    for (int msk=1; msk<32; msk<<=1) m = fmaxf(m, __shfl_xor(m, msk));
    float s = 0.f;
    for (int it=0; it<nit; ++it) {
      const int idx = start + it*32 + lane;
      if (idx < end) {
        const int2 p = ldnt(&cvp[idx]);
        const float x = f1r + f2in[p.x];
        s += __expf(((x>0.f)?x:LEAKY*x) - m);
      }
    }
    #pragma unroll
    for (int msk=1; msk<32; msk<<=1) s += __shfl_xor(s, msk);
    const float lgs = LG / s;
    float a[16];
    #pragma unroll
    for (int k=0;k<16;++k) a[k]=0.f;
    for (int it=0; it<nit; ++it) {
      const int idx = start + it*32 + lane;
      if (idx < end) {
        const int2 p = ldnt(&cvp[idx]);
        const float x = f1r + f2in[p.x];
        const float coef = (1.f-LG)*__int_as_float(p.y) + __expf(((x>0.f)?x:LEAKY*x) - m)*lgs;
        const ushort_t* zp = Zb + (size_t)p.x*NC;
        #pragma unroll
        for (int k=0;k<16;++k) a[k] += coef * bf16f(zp[k]);
      }
    }
    #pragma unroll
    for (int msk=1; msk<32; msk<<=1) {
      #pragma unroll
      for (int k=0;k<16;++k) a[k] += __shfl_xor(a[k], msk);
    }
    if (lane == 0) {
      #pragma unroll
      for (int k=0;k<16;++k) Zoutb[(size_t)row*NC + k] = f2bf(a[k]);
      float s1=0.f, s2=0.f;
      #pragma unroll
      for (int k=0;k<16;++k) { s1 += a[k]*a1v[k]; s2 += a[k]*a2v[k]; }
      f1out[row]=s1; f2out[row]=s2;
    }
  }
}

// ---------------- hop 2 fused with the per-node 3-hop attention mix ----------------
__global__ __launch_bounds__(256) void k_hop2mix(const int* __restrict__ rowptr,
    const int2* __restrict__ cvp,
    const ushort_t* __restrict__ Z1b, const float* __restrict__ f1in,
    const float* __restrict__ f2in, const float* __restrict__ Z0,
    const float* __restrict__ Wat, float* __restrict__ outp)
{
  __shared__ __align__(16) int2 rowbuf[8][64];
  const int t = threadIdx.x;
  const int lane = t & 31;
  const int hw = t >> 5;
  const int row = blockIdx.x*8 + hw;
  if (row >= NN) return;
  const int start = rowptr[row], end = rowptr[row+1];
  const int deg = end - start;
  const int c = lane & 15, g = (lane >> 4) & 1;

  if (deg > 64) {
    const float f1r = f1in[row];
    const int nit = (deg + 31) >> 5;
    float m = -1e30f;
    for (int it=0; it<nit; ++it) {
      const int idx = start + it*32 + lane;
      if (idx < end) {
        const float x = f1r + f2in[ldnt(&cvp[idx]).x];
        m = fmaxf(m, (x>0.f)?x:LEAKY*x);
      }
    }
    #pragma unroll
    for (int msk=1; msk<32; msk<<=1) m = fmaxf(m, __shfl_xor(m, msk));
    float s = 0.f;
    for (int it=0; it<nit; ++it) {
      const int idx = start + it*32 + lane;
      if (idx < end) {
        const float x = f1r + f2in[ldnt(&cvp[idx]).x];
        s += __expf(((x>0.f)?x:LEAKY*x) - m);
      }
    }
    #pragma unroll
    for (int msk=1; msk<32; msk<<=1) s += __shfl_xor(s, msk);
    const float lgs = LG / s;
    float a[16];
    #pragma unroll
    for (int k=0;k<16;++k) a[k]=0.f;
    for (int it=0; it<nit; ++it) {
      const int idx = start + it*32 + lane;
      if (idx < end) {
        const int2 p = ldnt(&cvp[idx]);
        const float x = f1r + f2in[p.x];
        const float coef = (1.f-LG)*__int_as_float(p.y) + __expf(((x>0.f)?x:LEAKY*x) - m)*lgs;
        const ushort_t* zp = Z1b + (size_t)p.x*NC;
        #pragma unroll
        for (int k=0;k<16;++k) a[k] += coef * bf16f(zp[k]);
      }
    }
    #pragma unroll
    for (int msk=1; msk<32; msk<<=1) {
      #pragma unroll
      for (int k=0;k<16;++k) a[k] += __shfl_xor(a[k], msk);
    }
    if (lane == 0) {
      float t0=0.f, t1=0.f, t2=0.f;
      for (int k=0;k<16;++k) {
        const float w = Wat[(size_t)row*NC + k];
        t0 += Z0[(size_t)row*NC + k]*w;
        t1 += bf16f(Z1b[(size_t)row*NC + k])*w;
        t2 += a[k]*w;
      }
      const float mm = fmaxf(t0, fmaxf(t1, t2));
      const float q0 = __expf(t0-mm), q1 = __expf(t1-mm), q2 = __expf(t2-mm);
      const float inv = 1.f/(q0+q1+q2);
      for (int k=0;k<16;++k)
        outp[(size_t)row*NC + k] =
          (q0*Z0[(size_t)row*NC + k] + q1*bf16f(Z1b[(size_t)row*NC + k]) + q2*a[k])*inv;
    }
    return;
  }

  float accv = 0.f;
  if (deg > 0) {
    const float f1r = f1in[row];
    int cc0 = 0, cc1 = 0; float vv0 = 0.f, vv1 = 0.f;
    float e0 = -1e30f, e1 = -1e30f;
    if (lane < deg) {
      const int2 p = ldnt(&cvp[start + lane]);
      cc0 = p.x; vv0 = __int_as_float(p.y);
      const float x = f1r + f2in[cc0];
      e0 = (x > 0.f) ? x : LEAKY*x;
    }
    if (32 + lane < deg) {
      const int2 p = ldnt(&cvp[start + 32 + lane]);
      cc1 = p.x; vv1 = __int_as_float(p.y);
      const float x = f1r + f2in[cc1];
      e1 = (x > 0.f) ? x : LEAKY*x;
    }
    float m = fmaxf(e0, e1);
    #pragma unroll
    for (int msk=1; msk<32; msk<<=1) m = fmaxf(m, __shfl_xor(m, msk));
    const float ex0 = (lane < deg) ? __expf(e0 - m) : 0.f;
    const float ex1 = (32 + lane < deg) ? __expf(e1 - m) : 0.f;
    float s = ex0 + ex1;
    #pragma unroll
    for (int msk=1; msk<32; msk<<=1) s += __shfl_xor(s, msk);
    const float lgs = LG / s;
    const int npass = (deg + 3) >> 2;
    if (lane < deg)
      rowbuf[hw][lane] = make_int2(cc0, __float_as_int((1.f-LG)*vv0 + ex0*lgs));
    if (32 + lane < deg)
      rowbuf[hw][32 + lane] = make_int2(cc1, __float_as_int((1.f-LG)*vv1 + ex1*lgs));
    for (int z = deg + lane; z < 4*npass; z += 32) rowbuf[hw][z] = make_int2(0, 0);
    asm volatile("s_waitcnt lgkmcnt(0)" ::: "memory");
    for (int p0 = 0; p0 < npass; p0 += 8) {
      int4 pr[8]; ushort_t u0[8], u1[8];
      #pragma unroll
      for (int j=0;j<8;++j) {
        if (p0 + j < npass)
          pr[j] = *(const int4*)(&rowbuf[hw][(p0+j)*4 + g*2]);
        else
          pr[j] = make_int4(0, 0, 0, 0);
      }
      #pragma unroll
      for (int j=0;j<8;++j) {
        u0[j] = Z1b[(size_t)pr[j].x*NC + c];
        u1[j] = Z1b[(size_t)pr[j].z*NC + c];
      }
      #pragma unroll
      for (int j=0;j<8;++j) {
        accv += __int_as_float(pr[j].y) * bf16f(u0[j]);
        accv += __int_as_float(pr[j].w) * bf16f(u1[j]);
      }
    }
    accv += __shfl_xor(accv, 16);
  }
  if (g == 0) {
    const float z0v = Z0[(size_t)row*NC + c];
    const float z1v = bf16f(Z1b[(size_t)row*NC + c]);
    const float wv  = Wat[(size_t)row*NC + c];
    float t0 = z0v*wv, t1 = z1v*wv, t2 = accv*wv;
    #pragma unroll
    for (int msk=1; msk<16; msk<<=1) {
      t0 += __shfl_xor(t0, msk); t1 += __shfl_xor(t1, msk); t2 += __shfl_xor(t2, msk);
    }
    const float mm = fmaxf(t0, fmaxf(t1, t2));
    const float q0 = __expf(t0-mm), q1 = __expf(t1-mm), q2 = __expf(t2-mm);
    const float inv = 1.f/(q0+q1+q2);
    outp[(size_t)row*NC + c] = (q0*z0v + q1*z1v + q2*accv)*inv;
  }
}

extern "C" void kernel_launch(void* const* d_in, const int* in_sizes, int n_in,
                              void* d_out, int out_size, void* d_ws, size_t ws_size,
                              hipStream_t stream) {
  const float* X   = (const float*)d_in[0];
  const float* W0  = (const float*)d_in[1];
  const float* W1  = (const float*)d_in[2];
  const float* a1  = (const float*)d_in[3];
  const float* a2  = (const float*)d_in[4];
  const float* Wat = (const float*)d_in[5];
  const float* gcn = (const float*)d_in[6];
  const int*   ei  = (const int*)d_in[7];
  const int* src = ei;
  const int* dst = ei + NE;
  float* out = (float*)d_out;

  // workspace layout (element offsets; 16B alignment maintained)
  float* Z0      = (float*)d_ws;             // NN*NC f32 (for final mix)
  ushort_t* Z0b  = (ushort_t*)(Z0 + (size_t)NN*NC);  // NN*NC bf16 (hop1 gather table)
  ushort_t* Z1b  = Z0b + (size_t)NN*NC;      // NN*NC bf16 (hop2 gather table)
  float* fA1  = (float*)(Z1b + (size_t)NN*NC); // NN
  float* fA2  = fA1 + NN;                    // NN
  float* fB1  = fA2 + NN;                    // NN
  float* fB2  = fB1 + NN;                    // NN
  int* rowptr = (int*)(fB2 + NN);            // NN+4
  int* bcnt   = rowptr + (NN + 4);           // 256
  int* gcur   = bcnt + 256;                  // 256
  short* W0T  = (short*)(gcur + 256);        // 64*512 shorts (bf16 RNE)
  int2* cvp   = (int2*)(W0T + HIDN*FIN);     // NE int2 packed (col,val)
  int2* tmp   = cvp + NE;                    // NBUCK*SLACK int2 (dead after k_binB)

  k_w0t<<<(HIDN*FIN + 255)/256, 256, 0, stream>>>(W0, W0T, bcnt, gcur);
  k_mlpA<<<MLP_BLKS + NBINA, 512, 0, stream>>>(X, W0T, W1, a1, a2, Z0, Z0b, fA1, fA2,
                                               src, dst, gcn, bcnt, gcur, tmp);
  k_binB<<<NBUCK, 512, 0, stream>>>(bcnt, tmp, rowptr, cvp);
  k_hop<<<12500, 256, 0, stream>>>(rowptr, cvp, Z0b, fA1, fA2, Z1b, fB1, fB2, a1, a2);
  k_hop2mix<<<12500, 256, 0, stream>>>(rowptr, cvp, Z1b, fB1, fB2, Z0, Wat, out);
}